// Round 16
// baseline (120.481 us; speedup 1.0000x reference)
//
#include <hip/hip_runtime.h>

// Fused cross-attention, MI355X gfx950. B=4, LQ=1024, LKV=4096, C=256, H=8, d=32, Z=1024.
//
// R16 = R15 + split=8 (2048 blocks = 8 blocks/CU queued; safe now that nt
// stores keep partials out of L2 — R14's split-8 regression was cached-write
// thrash) + combine fused into proj_out: attn writes Opart FRAGMENT-PACKED
// f32, fused tail reads contiguous 2KB wave-loads, sums partials, normalizes
// per k-chunk (k = head), converts and does the Wp MFMA. Removes the 4MB Xws
// round-trip and one launch.
//
//   prep_all:   W pack + pos pack (bf16*log2e) + kv pack + q pack (elementwise)
//   proj_qkv:   Khp[b][h][key][32]; Vsp (sigma-permuted); Qhp[b][h][qrow][32]
//   attn:       fixed-max (M=0) flash attention, KV-split 8, LDS-free, QG=2,
//               nt packed-f32 partial stores
//   proj_out_c: sum partials + normalize + out = fp32(X @ Wp^T + bp)
//
// mfma_f32_16x16x32_bf16 layouts (m89-verified):
//   A: row=l&15, k=(l>>4)*8+i ; B: col=l&15, k=(l>>4)*8+i ; C: col=l&15, row=(l>>4)*4+r

typedef __attribute__((ext_vector_type(8))) short bf16x8;
typedef __attribute__((ext_vector_type(4))) float f32x4;
typedef __attribute__((ext_vector_type(4))) unsigned short u16x4;

#define MFMA16(a, b, c) __builtin_amdgcn_mfma_f32_16x16x32_bf16((a), (b), (c), 0, 0, 0)

__device__ __forceinline__ unsigned short f2bf(float f) {
  return __builtin_bit_cast(unsigned short, static_cast<__bf16>(f));  // RNE
}
__device__ __forceinline__ float bf2f(unsigned short u) {
  return __builtin_bit_cast(float, ((unsigned)u) << 16);
}

// ---------------------------------------------------------------- prep_all
__global__ __launch_bounds__(256) void prep_all(const float* __restrict__ Wq,
                                                const float* __restrict__ Wk,
                                                const float* __restrict__ Wv,
                                                const float* __restrict__ Wp,
                                                const float* __restrict__ pos,
                                                const float* __restrict__ Xq,
                                                const float* __restrict__ Xkv,
                                                const float* __restrict__ q_ape,
                                                const float* __restrict__ k_ape,
                                                unsigned short* __restrict__ wout,
                                                unsigned short* __restrict__ pfb,
                                                unsigned short* __restrict__ kvp,
                                                unsigned short* __restrict__ qp,
                                                int posBlocks) {
  int bx = blockIdx.x;
  if (bx < posBlocks) {
    const int s4 = bx * 256 + threadIdx.x;  // 2,097,152 threads, 4 floats each
    const int zk4 = s4 & 255, q = (s4 >> 8) & 1023, h = s4 >> 18;
    const float4 v = *(const float4*)(pos + ((size_t)s4 << 2));
    const int kt = zk4 >> 4, c = (zk4 >> 2) & 3, g = zk4 & 3;
    const float L = 1.4426950408889634f;
    u16x4 o = { f2bf(v.x * L), f2bf(v.y * L), f2bf(v.z * L), f2bf(v.w * L) };
    *(u16x4*)(pfb + (size_t)((h << 6) + (q >> 4)) * 16384 + ((kt << 2) + c) * 256 + ((q & 15) << 4) + (g << 2)) = o;
    return;
  }
  bx -= posBlocks;
  if (bx < 128) {
    const int idx = bx * 256 + threadIdx.x;  // 32768 threads
    const int which = idx >> 13, rem = idx & 8191;
    const int o = rem >> 5, colb = (rem & 31) << 3;
    const float* src = (which == 0) ? Wq : (which == 1) ? Wk : (which == 2) ? Wv : Wp;
    float4 v0 = *(const float4*)(src + (size_t)o * 256 + colb);
    float4 v1 = *(const float4*)(src + (size_t)o * 256 + colb + 4);
    if (which == 0) {  // fold softmax scale and log2(e) into Wq
      const float qs = 0.17677669529663687f * 1.4426950408889634f;
      v0.x *= qs; v0.y *= qs; v0.z *= qs; v0.w *= qs;
      v1.x *= qs; v1.y *= qs; v1.z *= qs; v1.w *= qs;
    }
    const int n = o >> 4, x = o & 15, k = colb >> 5, g = (colb & 31) >> 3;
    unsigned short* dst = wout + (which << 16) + n * 4096 + k * 512 + x * 32 + g * 8;
    u16x4 a = { f2bf(v0.x), f2bf(v0.y), f2bf(v0.z), f2bf(v0.w) };
    u16x4 b = { f2bf(v1.x), f2bf(v1.y), f2bf(v1.z), f2bf(v1.w) };
    *(u16x4*)dst = a;
    *(u16x4*)(dst + 4) = b;
    return;
  }
  bx -= 128;
  if (bx < 2048) {
    const int idx = bx * 256 + threadIdx.x;  // 524,288 threads: 16384 rows x 32 col-chunks
    const int row = idx >> 5, c8 = idx & 31;
    const int col = c8 << 3, lq = row & 4095;
    const float* xp = Xkv + (size_t)row * 256 + col;
    float4 v0 = *(const float4*)xp, v1 = *(const float4*)(xp + 4);
    if (lq >= 1024) {  // k_ape covers kv rows [Z, LKV)
      const float* ap = k_ape + (size_t)(lq - 1024) * 256 + col;
      const float4 a0 = *(const float4*)ap, a1 = *(const float4*)(ap + 4);
      v0.x += a0.x; v0.y += a0.y; v0.z += a0.z; v0.w += a0.w;
      v1.x += a1.x; v1.y += a1.y; v1.z += a1.z; v1.w += a1.w;
    }
    const int k = c8 >> 2, g = c8 & 3;
    unsigned short* dst = kvp + (size_t)(row >> 4) * 4096 + k * 512 + (row & 15) * 32 + g * 8;
    u16x4 a = { f2bf(v0.x), f2bf(v0.y), f2bf(v0.z), f2bf(v0.w) };
    u16x4 b = { f2bf(v1.x), f2bf(v1.y), f2bf(v1.z), f2bf(v1.w) };
    *(u16x4*)dst = a;
    *(u16x4*)(dst + 4) = b;
    return;
  }
  bx -= 2048;
  {
    const int idx = bx * 256 + threadIdx.x;  // 131,072 threads: 4096 rows x 32 chunks
    const int row = idx >> 5, c8 = idx & 31;
    const int col = c8 << 3, arow = row & 1023;
    const float* xp = Xq + (size_t)row * 256 + col;
    const float* ap = q_ape + (size_t)arow * 256 + col;
    const float4 v0 = *(const float4*)xp, v1 = *(const float4*)(xp + 4);
    const float4 a0 = *(const float4*)ap, a1 = *(const float4*)(ap + 4);
    const int k = c8 >> 2, g = c8 & 3;
    unsigned short* dst = qp + (size_t)(row >> 4) * 4096 + k * 512 + (row & 15) * 32 + g * 8;
    u16x4 a = { f2bf(v0.x + a0.x), f2bf(v0.y + a0.y), f2bf(v0.z + a0.z), f2bf(v0.w + a0.w) };
    u16x4 b = { f2bf(v1.x + a1.x), f2bf(v1.y + a1.y), f2bf(v1.z + a1.z), f2bf(v1.w + a1.w) };
    *(u16x4*)dst = a;
    *(u16x4*)(dst + 4) = b;
  }
}

// ---------------------------------------------------------------- proj_qkv
// blocks [0,512): K -> Khp[b][h][key][32]
// blocks [512,1024): V -> Vsp sigma store
// blocks [1024,1152): Q -> Qhp[b][h][qrow][32] (head-packed)
__global__ __launch_bounds__(256, 4) void proj_qkv(const unsigned short* __restrict__ kvp,
                                                   const unsigned short* __restrict__ qp,
                                                   const unsigned short* __restrict__ Wqb,
                                                   const unsigned short* __restrict__ Wkb,
                                                   const unsigned short* __restrict__ Wvb,
                                                   unsigned short* __restrict__ Qhp,
                                                   unsigned short* __restrict__ Khp,
                                                   unsigned short* __restrict__ Vsp) {
  const int tid = threadIdx.x;
  const int w = tid >> 6, lane = tid & 63, x = lane & 15, g = lane >> 4;
  const int rg = w & 1, nh = w >> 1;
  const int bx = blockIdx.x;
  if (bx < 1024) {
    const bool isV = bx >= 512;
    const int bk = isV ? bx - 512 : bx;
    const int rbase = bk * 32 + rg * 16;
    const unsigned short* ap = kvp + (size_t)(rbase >> 4) * 4096 + x * 32 + g * 8;
    bf16x8 a[8];
#pragma unroll
    for (int k = 0; k < 8; ++k) a[k] = *(const bf16x8*)(ap + k * 512);
    const unsigned short* Wb = isV ? Wvb : Wkb;
    f32x4 acc[8];
#pragma unroll
    for (int n = 0; n < 8; ++n) acc[n] = (f32x4){0.f, 0.f, 0.f, 0.f};
#pragma unroll
    for (int k = 0; k < 8; ++k)
#pragma unroll
      for (int n0 = 0; n0 < 8; ++n0) {
        const bf16x8 bw = *(const bf16x8*)(Wb + (size_t)(nh * 8 + n0) * 4096 + k * 512 + x * 32 + g * 8);
        acc[n0] = MFMA16(a[k], bw, acc[n0]);
      }
    if (!isV) {
      const int b2 = rbase >> 12, kk0 = (rbase & 4095) + g * 4;
#pragma unroll
      for (int n0 = 0; n0 < 8; ++n0) {
        const int n = nh * 8 + n0, hh = n >> 1, dd = ((n & 1) << 4) + x;
        unsigned short* kp = Khp + (size_t)(b2 * 8 + hh) * 131072;
#pragma unroll
        for (int r = 0; r < 4; ++r)
          kp[(size_t)(kk0 + r) * 32 + dd] = f2bf(acc[n0][r]);
      }
    } else {
      // sigma: key slot m=16c0+4g+r stored at ks=c0&1, i=4*(c0>>1)+r
      const int b2 = rbase >> 12, T = (rbase >> 6) & 63, c0 = (rbase >> 4) & 3;
      const int ks = c0 & 1, ih = (c0 >> 1) << 2;
#pragma unroll
      for (int n0 = 0; n0 < 8; ++n0) {
        const int n = nh * 8 + n0, hh = n >> 1, dh = n & 1;
        u16x4 o = { f2bf(acc[n0][0]), f2bf(acc[n0][1]), f2bf(acc[n0][2]), f2bf(acc[n0][3]) };
        *(u16x4*)(Vsp + (size_t)(b2 * 8 + hh) * 131072 + T * 2048 + ks * 1024 + dh * 512 + g * 128 + x * 8 + ih) = o;
      }
    }
  } else {
    const int bq = bx - 1024;  // 0..127
    const int rbase = bq * 32 + rg * 16;
    const unsigned short* ap = qp + (size_t)(rbase >> 4) * 4096 + x * 32 + g * 8;
    bf16x8 a[8];
#pragma unroll
    for (int k = 0; k < 8; ++k) a[k] = *(const bf16x8*)(ap + k * 512);
    f32x4 acc[8];
#pragma unroll
    for (int n = 0; n < 8; ++n) acc[n] = (f32x4){0.f, 0.f, 0.f, 0.f};
#pragma unroll
    for (int k = 0; k < 8; ++k)
#pragma unroll
      for (int n0 = 0; n0 < 8; ++n0) {
        const bf16x8 bw = *(const bf16x8*)(Wqb + (size_t)(nh * 8 + n0) * 4096 + k * 512 + x * 32 + g * 8);
        acc[n0] = MFMA16(a[k], bw, acc[n0]);
      }
    // head-packed store: Qhp[b][h][qrow][32]
    const int b2 = rbase >> 10, qr0 = (rbase & 1023) + g * 4;
#pragma unroll
    for (int n0 = 0; n0 < 8; ++n0) {
      const int n = nh * 8 + n0, hh = n >> 1, dd = ((n & 1) << 4) + x;
      unsigned short* qpn = Qhp + (size_t)(b2 * 8 + hh) * 32768;
#pragma unroll
      for (int r = 0; r < 4; ++r)
        qpn[(size_t)(qr0 + r) * 32 + dd] = f2bf(acc[n0][r]);
    }
  }
}

// ---------------------------------------------------------------- attn
// 1-D grid of 256*SPLIT blocks, XCD decode h=bid&7 (bid%8 -> XCD round-robin;
// R12 verified FETCH 76->19MB). b=(bid>>3)&3, qt=(bid>>5)&7, z=bid>>8.
// Wave: 32 q-rows (QG=2), groups SEQUENTIAL. Opart written NONTEMPORAL in
// fragment-packed f32 layout (A-frag order for the fused tail); R14 showed
// cached partial writes evict the K/V+pf L2 set. LDS-free. (256,4) cap.
template <int SPLIT, bool PF>
__global__ __launch_bounds__(256, 4) void
attn_fused(const unsigned short* __restrict__ Qhp,
           const unsigned short* __restrict__ Khp,
           const unsigned short* __restrict__ Vsp,
           const void* __restrict__ pos,
           unsigned short* __restrict__ Xo,
           float* __restrict__ Opart,
           float* __restrict__ lpart) {
  const int tid = threadIdx.x;
  const int w = tid >> 6, lane = tid & 63, x = lane & 15, g = lane >> 4;
  const int bid = blockIdx.x;
  const int h = bid & 7, b = (bid >> 3) & 3, qt = (bid >> 5) & 7, z = bid >> 8;
  const int qrow0 = qt * 128 + w * 32;
  const int NT = 64 / SPLIT;

  const unsigned short* Qpl = Qhp + (size_t)(b * 8 + h) * 32768;
  const bf16x8 aq0 = *(const bf16x8*)(Qpl + (size_t)(qrow0 + x) * 32 + g * 8);
  const bf16x8 aq1 = *(const bf16x8*)(Qpl + (size_t)(qrow0 + 16 + x) * 32 + g * 8);
  const unsigned short* Kpl = Khp + (size_t)(b * 8 + h) * 131072 + x * 32 + g * 8;
  const unsigned short* Vpl = Vsp + (size_t)(b * 8 + h) * 131072 + g * 128 + x * 8;
  // PF: bf16 pre-scaled bias, fragment-packed. !PF: raw fp32 [h][q][zkey].
  const unsigned short* pq0 = PF ? (const unsigned short*)pos + (size_t)((h << 6) + (qt << 3) + (w << 1)) * 16384 : nullptr;
  const unsigned short* pq1 = PF ? pq0 + 16384 : nullptr;
  const float* pr0 = PF ? nullptr : (const float*)pos + (size_t)((h << 10) + qrow0 + x) * 1024;
  const float* pr1 = PF ? nullptr : (const float*)pos + (size_t)((h << 10) + qrow0 + 16 + x) * 1024;
  const f32x4 zc = {0.f, 0.f, 0.f, 0.f};

  f32x4 o00 = zc, o01 = zc, o10 = zc, o11 = zc;
  float ls0 = 0.f, ls1 = 0.f;

  bf16x8 ka[4], va[4];
  // preload tile t = z
#pragma unroll
  for (int c = 0; c < 4; ++c)
    ka[c] = *(const bf16x8*)(Kpl + (size_t)((z << 6) + c * 16) * 32);
#pragma unroll
  for (int j = 0; j < 4; ++j)
    va[j] = *(const bf16x8*)(Vpl + (z << 11) + (j << 9));

// One q-group: QK -> [bias] -> exp2/lsum -> pack -> PV. s[4]/pa transient.
#define GROUP(AQ, PQ, PR, LS, OA, OB, T, BIAS)                                               \
  do {                                                                                       \
    f32x4 s[4];                                                                              \
    _Pragma("unroll")                                                                        \
    for (int c = 0; c < 4; ++c) s[c] = MFMA16(ka[c], AQ, zc);                                \
    if (BIAS) {                                                                              \
      if (PF) {                                                                              \
        _Pragma("unroll")                                                                    \
        for (int c = 0; c < 4; ++c) {                                                        \
          const u16x4 p = *(const u16x4*)(PQ + ((T) << 10) + (c << 8) + (x << 4) + (g << 2)); \
          s[c][0] += bf2f(p[0]); s[c][1] += bf2f(p[1]);                                      \
          s[c][2] += bf2f(p[2]); s[c][3] += bf2f(p[3]);                                      \
        }                                                                                    \
      } else {                                                                               \
        const float LOG2E = 1.4426950408889634f;                                             \
        _Pragma("unroll")                                                                    \
        for (int c = 0; c < 4; ++c) {                                                        \
          const float4 p = *(const float4*)(PR + ((T) << 6) + c * 16 + g * 4);               \
          s[c][0] = fmaf(p.x, LOG2E, s[c][0]); s[c][1] = fmaf(p.y, LOG2E, s[c][1]);          \
          s[c][2] = fmaf(p.z, LOG2E, s[c][2]); s[c][3] = fmaf(p.w, LOG2E, s[c][3]);          \
        }                                                                                    \
      }                                                                                      \
    }                                                                                        \
    _Pragma("unroll")                                                                        \
    for (int c = 0; c < 4; ++c)                                                              \
      _Pragma("unroll")                                                                      \
      for (int r = 0; r < 4; ++r) {                                                          \
        s[c][r] = __builtin_amdgcn_exp2f(s[c][r]); LS += s[c][r];                            \
      }                                                                                      \
    bf16x8 pa0, pa1;                                                                         \
    _Pragma("unroll")                                                                        \
    for (int r = 0; r < 4; ++r) {                                                            \
      pa0[r] = (short)f2bf(s[0][r]); pa0[4 + r] = (short)f2bf(s[2][r]);                      \
      pa1[r] = (short)f2bf(s[1][r]); pa1[4 + r] = (short)f2bf(s[3][r]);                      \
    }                                                                                        \
    OA = MFMA16(pa0, va[0], OA); OB = MFMA16(pa0, va[1], OB);                                \
    OA = MFMA16(pa1, va[2], OA); OB = MFMA16(pa1, va[3], OB);                                \
  } while (0)

#define TILE(T, BIAS)                                                                        \
  do {                                                                                       \
    const int tp = ((T) + SPLIT <= 63) ? (T) + SPLIT : (T);                                  \
    GROUP(aq0, pq0, pr0, ls0, o00, o01, T, BIAS);                                            \
    GROUP(aq1, pq1, pr1, ls1, o10, o11, T, BIAS);                                            \
    _Pragma("unroll")                                                                        \
    for (int c = 0; c < 4; ++c)  /* reuse-prefetch K for tile tp */                          \
      ka[c] = *(const bf16x8*)(Kpl + (size_t)((tp << 6) + c * 16) * 32);                     \
    _Pragma("unroll")                                                                        \
    for (int j = 0; j < 4; ++j)  /* reuse-prefetch V for tile tp */                          \
      va[j] = *(const bf16x8*)(Vpl + (tp << 11) + (j << 9));                                 \
  } while (0)

  const int nb = 16 / SPLIT;  // biased iterations (split 1,2,4,8 divide 16)
  int t = z;
  for (int i = 0; i < nb; ++i) { TILE(t, true);  t += SPLIT; }
  for (int i = nb; i < NT; ++i) { TILE(t, false); t += SPLIT; }
#undef TILE
#undef GROUP

  ls0 += __shfl_xor(ls0, 16); ls0 += __shfl_xor(ls0, 32);
  ls1 += __shfl_xor(ls1, 16); ls1 += __shfl_xor(ls1, 32);

  if (SPLIT == 1) {
    // fragment-packed X write (matches proj_out's packed A reads)
    const float inv0 = 1.f / ls0, inv1 = 1.f / ls1;
    const int rowblk = (b << 6) + (qt << 3) + (w << 1);
#pragma unroll
    for (int r = 0; r < 4; ++r) {
      const float ir0 = __shfl(inv0, g * 4 + r, 64);
      const float ir1 = __shfl(inv1, g * 4 + r, 64);
      unsigned short* d0 = Xo + (size_t)rowblk * 4096 + h * 512 + (g * 4 + r) * 32;
      unsigned short* d1 = Xo + (size_t)(rowblk + 1) * 4096 + h * 512 + (g * 4 + r) * 32;
      d0[x] = f2bf(o00[r] * ir0);
      d0[16 + x] = f2bf(o01[r] * ir0);
      d1[x] = f2bf(o10[r] * ir1);
      d1[16 + x] = f2bf(o11[r] * ir1);
    }
  } else {
    if (g == 0) {
      __builtin_nontemporal_store(ls0, &lpart[(size_t)z * 32768 + ((b << 10) + qrow0 + x) * 8 + h]);
      __builtin_nontemporal_store(ls1, &lpart[(size_t)z * 32768 + ((b << 10) + qrow0 + 16 + x) * 8 + h]);
    }
    // fragment-packed f32 partials: row (g*4+r) of rowblk, cols h*32 + {x, 16+x}
    const int rowblk = (b << 6) + (qt << 3) + (w << 1);
#pragma unroll
    for (int r = 0; r < 4; ++r) {
      float* b0 = Opart + (size_t)z * 1048576 + (size_t)rowblk * 4096 + h * 512 + (g * 4 + r) * 32;
      float* b1 = b0 + 4096;
      __builtin_nontemporal_store(o00[r], b0 + x);
      __builtin_nontemporal_store(o01[r], b0 + 16 + x);
      __builtin_nontemporal_store(o10[r], b1 + x);
      __builtin_nontemporal_store(o11[r], b1 + 16 + x);
    }
  }
}

// ---------------------------------------------------------------- proj_out_c
// Fused combine + out-projection (split>1 path). Opart is fragment-packed f32:
// [z][rowblk][k=8][x=16][g=4][i=8]. Lane (x,g) sums z-partials (contiguous 2KB
// wave-loads), normalizes by inv_l(row=x, h=k) from lpart, converts to bf16
// A-fragments, then out = fp32(X @ Wp^T + bp).
__global__ __launch_bounds__(256) void proj_out_c(const float* __restrict__ Opart,
                                                  const float* __restrict__ lpart,
                                                  const unsigned short* __restrict__ Wb,
                                                  const float* __restrict__ bias,
                                                  float* __restrict__ out, int split) {
  const int tid = threadIdx.x;
  const int w = tid >> 6, lane = tid & 63, x = lane & 15, g = lane >> 4;
  const int blk = blockIdx.x, rbase = blk << 4;
  const int cb = w << 6;

  // denominators for row rbase+x, all 8 heads
  float l[8];
#pragma unroll
  for (int k = 0; k < 8; ++k) l[k] = 0.f;
  for (int zz = 0; zz < split; ++zz) {
    const float* lp = lpart + (size_t)zz * 32768 + (size_t)(rbase + x) * 8;
    const float4 l0 = *(const float4*)lp, l1 = *(const float4*)(lp + 4);
    l[0] += l0.x; l[1] += l0.y; l[2] += l0.z; l[3] += l0.w;
    l[4] += l1.x; l[5] += l1.y; l[6] += l1.z; l[7] += l1.w;
  }
#pragma unroll
  for (int k = 0; k < 8; ++k) l[k] = 1.f / l[k];

  bf16x8 a[8];
#pragma unroll
  for (int k = 0; k < 8; ++k) {
    float s[8];
#pragma unroll
    for (int i = 0; i < 8; ++i) s[i] = 0.f;
    for (int zz = 0; zz < split; ++zz) {
      const float* op = Opart + (size_t)zz * 1048576 + (size_t)blk * 4096 + k * 512 + x * 32 + g * 8;
      const float4 v0 = *(const float4*)op, v1 = *(const float4*)(op + 4);
      s[0] += v0.x; s[1] += v0.y; s[2] += v0.z; s[3] += v0.w;
      s[4] += v1.x; s[5] += v1.y; s[6] += v1.z; s[7] += v1.w;
    }
    bf16x8 av;
#pragma unroll
    for (int i = 0; i < 8; ++i) av[i] = (short)f2bf(s[i] * l[k]);
    a[k] = av;
  }

  f32x4 acc[4];
#pragma unroll
  for (int n = 0; n < 4; ++n) acc[n] = (f32x4){0.f, 0.f, 0.f, 0.f};
#pragma unroll
  for (int k = 0; k < 8; ++k)
#pragma unroll
    for (int n = 0; n < 4; ++n) {
      const bf16x8 bw = *(const bf16x8*)(Wb + (size_t)((w << 2) + n) * 4096 + k * 512 + x * 32 + g * 8);
      acc[n] = MFMA16(a[k], bw, acc[n]);
    }
#pragma unroll
  for (int n = 0; n < 4; ++n) {
    const float bv = bias[cb + n * 16 + x];
#pragma unroll
    for (int r = 0; r < 4; ++r)
      out[(size_t)(rbase + g * 4 + r) * 256 + cb + n * 16 + x] = acc[n][r] + bv;
  }
}

// ---------------------------------------------------------------- proj_out (split==1 fallback)
__global__ __launch_bounds__(256) void proj_out(const unsigned short* __restrict__ Xp,
                                                const unsigned short* __restrict__ Wb,
                                                const float* __restrict__ bias,
                                                float* __restrict__ out) {
  const int tid = threadIdx.x;
  const int w = tid >> 6, lane = tid & 63, x = lane & 15, g = lane >> 4;
  const int rbase = blockIdx.x << 4;
  const int cb = w << 6;
  const unsigned short* ap = Xp + (size_t)blockIdx.x * 4096 + x * 32 + g * 8;
  bf16x8 a[8];
#pragma unroll
  for (int k = 0; k < 8; ++k) a[k] = *(const bf16x8*)(ap + k * 512);
  f32x4 acc[4];
#pragma unroll
  for (int n = 0; n < 4; ++n) acc[n] = (f32x4){0.f, 0.f, 0.f, 0.f};
#pragma unroll
  for (int k = 0; k < 8; ++k)
#pragma unroll
    for (int n = 0; n < 4; ++n) {
      const bf16x8 bw = *(const bf16x8*)(Wb + (size_t)((w << 2) + n) * 4096 + k * 512 + x * 32 + g * 8);
      acc[n] = MFMA16(a[k], bw, acc[n]);
    }
#pragma unroll
  for (int n = 0; n < 4; ++n) {
    const float bv = bias[cb + n * 16 + x];
#pragma unroll
    for (int r = 0; r < 4; ++r)
      out[(size_t)(rbase + g * 4 + r) * 256 + cb + n * 16 + x] = acc[n][r] + bv;
  }
}

// ---------------------------------------------------------------- launch
extern "C" void kernel_launch(void* const* d_in, const int* in_sizes, int n_in,
                              void* d_out, int out_size, void* d_ws, size_t ws_size,
                              hipStream_t stream) {
  const float* q        = (const float*)d_in[0];
  const float* kv       = (const float*)d_in[1];
  const float* q_ape    = (const float*)d_in[2];
  const float* k_ape    = (const float*)d_in[3];
  const float* attn_pos = (const float*)d_in[4];
  const float* Wq       = (const float*)d_in[5];
  const float* Wk       = (const float*)d_in[6];
  const float* Wv       = (const float*)d_in[7];
  const float* Wp       = (const float*)d_in[8];
  const float* bp       = (const float*)d_in[9];
  float* out = (float*)d_out;

  unsigned short* wsb = (unsigned short*)d_ws;
  unsigned short* Wqb = wsb;                 // 4 x 65536 shorts (fragment-packed)
  unsigned short* Wkb = wsb + 65536;
  unsigned short* Wvb = wsb + 131072;
  unsigned short* Wpb = wsb + 196608;
  unsigned short* Qhp = wsb + 262144;        // [4][8][1024][32] head-packed
  unsigned short* Khp = wsb + 1310720;       // [4][8][4096][32]
  unsigned short* Vsp = wsb + 5505024;       // sigma-permuted V
  unsigned short* Xws = wsb + 9699328;       // fragment-packed X (split==1 path)
  unsigned short* kvp = wsb + 10747904;      // packed kv+ape (8MB)
  unsigned short* qp  = wsb + 14942208;      // packed q+ape  (2MB)

  const size_t L0  = 31981568ull;            // bytes of everything above
  const size_t PFB = 16777216ull;            // pf bf16 bytes
  const size_t PS  = 4325376ull;             // per-split Opart+lpart bytes
  int split; bool havepf;
  if      (ws_size >= L0 + PFB + 8 * PS) { split = 8; havepf = true; }
  else if (ws_size >= L0 + PFB + 4 * PS) { split = 4; havepf = true; }
  else if (ws_size >= L0 + 4 * PS)       { split = 4; havepf = false; }
  else if (ws_size >= L0 + 2 * PS)       { split = 2; havepf = false; }
  else                                   { split = 1; havepf = false; }
  unsigned short* pfb = (unsigned short*)((char*)d_ws + L0);
  float* Opart = (float*)((char*)d_ws + L0 + (havepf ? PFB : 0));
  float* lpart = Opart + (size_t)split * 1048576;

  const int posBlocks = havepf ? 8192 : 0;
  prep_all<<<posBlocks + 128 + 2048 + 512, 256, 0, stream>>>(
      Wq, Wk, Wv, Wp, attn_pos, q, kv, q_ape, k_ape, wsb, pfb, kvp, qp, posBlocks);
  proj_qkv<<<1152, 256, 0, stream>>>(kvp, qp, Wqb, Wkb, Wvb, Qhp, Khp, Vsp);
  if (havepf && split == 8)
    attn_fused<8, true><<<2048, 256, 0, stream>>>(Qhp, Khp, Vsp, pfb, Xws, Opart, lpart);
  else if (havepf)
    attn_fused<4, true><<<1024, 256, 0, stream>>>(Qhp, Khp, Vsp, pfb, Xws, Opart, lpart);
  else if (split == 4)
    attn_fused<4, false><<<1024, 256, 0, stream>>>(Qhp, Khp, Vsp, attn_pos, Xws, Opart, lpart);
  else if (split == 2)
    attn_fused<2, false><<<512, 256, 0, stream>>>(Qhp, Khp, Vsp, attn_pos, Xws, Opart, lpart);
  else
    attn_fused<1, false><<<256, 256, 0, stream>>>(Qhp, Khp, Vsp, attn_pos, Xws, Opart, lpart);
  if (split > 1)
    proj_out_c<<<256, 256, 0, stream>>>(Opart, lpart, Wpb, bp, out, split);
  else
    proj_out<<<256, 256, 0, stream>>>(Xws, Wpb, bp, out);
}

// Round 17
// 111.907 us; speedup vs baseline: 1.0766x; 1.0766x over previous
//
#include <hip/hip_runtime.h>

// Fused cross-attention, MI355X gfx950. B=4, LQ=1024, LKV=4096, C=256, H=8, d=32, Z=1024.
//
// R17 = R15's attn (split=4, QG=2, nt partial stores — measured best 39.4us)
// + FIXED fused tail: R16's proj_out_c was 45us because (a) 256 blocks = 1/CU
// and (b) runtime `split` blocked unrolling -> 64 serialized HBM loads/lane.
// Now: proj_out_c<SPLIT> (compile-time, z-loop unrolled -> full MLP), grid
// 1024 (rowblk x col-quarter, 4 blocks/CU). Opart stays fragment-packed f32
// nt (R14: cached partial writes evict the K/V+pf L2 set).
//
//   prep_all:   W pack + pos pack (bf16*log2e) + kv pack + q pack (elementwise)
//   proj_qkv:   Khp[b][h][key][32]; Vsp (sigma-permuted); Qhp[b][h][qrow][32]
//   attn:       fixed-max (M=0) flash attention, KV-split 4, LDS-free, QG=2
//   proj_out_c: sum partials + normalize + out = fp32(X @ Wp^T + bp)
//
// mfma_f32_16x16x32_bf16 layouts (m89-verified):
//   A: row=l&15, k=(l>>4)*8+i ; B: col=l&15, k=(l>>4)*8+i ; C: col=l&15, row=(l>>4)*4+r

typedef __attribute__((ext_vector_type(8))) short bf16x8;
typedef __attribute__((ext_vector_type(4))) float f32x4;
typedef __attribute__((ext_vector_type(4))) unsigned short u16x4;

#define MFMA16(a, b, c) __builtin_amdgcn_mfma_f32_16x16x32_bf16((a), (b), (c), 0, 0, 0)

__device__ __forceinline__ unsigned short f2bf(float f) {
  return __builtin_bit_cast(unsigned short, static_cast<__bf16>(f));  // RNE
}
__device__ __forceinline__ float bf2f(unsigned short u) {
  return __builtin_bit_cast(float, ((unsigned)u) << 16);
}

// ---------------------------------------------------------------- prep_all
__global__ __launch_bounds__(256) void prep_all(const float* __restrict__ Wq,
                                                const float* __restrict__ Wk,
                                                const float* __restrict__ Wv,
                                                const float* __restrict__ Wp,
                                                const float* __restrict__ pos,
                                                const float* __restrict__ Xq,
                                                const float* __restrict__ Xkv,
                                                const float* __restrict__ q_ape,
                                                const float* __restrict__ k_ape,
                                                unsigned short* __restrict__ wout,
                                                unsigned short* __restrict__ pfb,
                                                unsigned short* __restrict__ kvp,
                                                unsigned short* __restrict__ qp,
                                                int posBlocks) {
  int bx = blockIdx.x;
  if (bx < posBlocks) {
    const int s4 = bx * 256 + threadIdx.x;  // 2,097,152 threads, 4 floats each
    const int zk4 = s4 & 255, q = (s4 >> 8) & 1023, h = s4 >> 18;
    const float4 v = *(const float4*)(pos + ((size_t)s4 << 2));
    const int kt = zk4 >> 4, c = (zk4 >> 2) & 3, g = zk4 & 3;
    const float L = 1.4426950408889634f;
    u16x4 o = { f2bf(v.x * L), f2bf(v.y * L), f2bf(v.z * L), f2bf(v.w * L) };
    *(u16x4*)(pfb + (size_t)((h << 6) + (q >> 4)) * 16384 + ((kt << 2) + c) * 256 + ((q & 15) << 4) + (g << 2)) = o;
    return;
  }
  bx -= posBlocks;
  if (bx < 128) {
    const int idx = bx * 256 + threadIdx.x;  // 32768 threads
    const int which = idx >> 13, rem = idx & 8191;
    const int o = rem >> 5, colb = (rem & 31) << 3;
    const float* src = (which == 0) ? Wq : (which == 1) ? Wk : (which == 2) ? Wv : Wp;
    float4 v0 = *(const float4*)(src + (size_t)o * 256 + colb);
    float4 v1 = *(const float4*)(src + (size_t)o * 256 + colb + 4);
    if (which == 0) {  // fold softmax scale and log2(e) into Wq
      const float qs = 0.17677669529663687f * 1.4426950408889634f;
      v0.x *= qs; v0.y *= qs; v0.z *= qs; v0.w *= qs;
      v1.x *= qs; v1.y *= qs; v1.z *= qs; v1.w *= qs;
    }
    const int n = o >> 4, x = o & 15, k = colb >> 5, g = (colb & 31) >> 3;
    unsigned short* dst = wout + (which << 16) + n * 4096 + k * 512 + x * 32 + g * 8;
    u16x4 a = { f2bf(v0.x), f2bf(v0.y), f2bf(v0.z), f2bf(v0.w) };
    u16x4 b = { f2bf(v1.x), f2bf(v1.y), f2bf(v1.z), f2bf(v1.w) };
    *(u16x4*)dst = a;
    *(u16x4*)(dst + 4) = b;
    return;
  }
  bx -= 128;
  if (bx < 2048) {
    const int idx = bx * 256 + threadIdx.x;  // 524,288 threads: 16384 rows x 32 col-chunks
    const int row = idx >> 5, c8 = idx & 31;
    const int col = c8 << 3, lq = row & 4095;
    const float* xp = Xkv + (size_t)row * 256 + col;
    float4 v0 = *(const float4*)xp, v1 = *(const float4*)(xp + 4);
    if (lq >= 1024) {  // k_ape covers kv rows [Z, LKV)
      const float* ap = k_ape + (size_t)(lq - 1024) * 256 + col;
      const float4 a0 = *(const float4*)ap, a1 = *(const float4*)(ap + 4);
      v0.x += a0.x; v0.y += a0.y; v0.z += a0.z; v0.w += a0.w;
      v1.x += a1.x; v1.y += a1.y; v1.z += a1.z; v1.w += a1.w;
    }
    const int k = c8 >> 2, g = c8 & 3;
    unsigned short* dst = kvp + (size_t)(row >> 4) * 4096 + k * 512 + (row & 15) * 32 + g * 8;
    u16x4 a = { f2bf(v0.x), f2bf(v0.y), f2bf(v0.z), f2bf(v0.w) };
    u16x4 b = { f2bf(v1.x), f2bf(v1.y), f2bf(v1.z), f2bf(v1.w) };
    *(u16x4*)dst = a;
    *(u16x4*)(dst + 4) = b;
    return;
  }
  bx -= 2048;
  {
    const int idx = bx * 256 + threadIdx.x;  // 131,072 threads: 4096 rows x 32 chunks
    const int row = idx >> 5, c8 = idx & 31;
    const int col = c8 << 3, arow = row & 1023;
    const float* xp = Xq + (size_t)row * 256 + col;
    const float* ap = q_ape + (size_t)arow * 256 + col;
    const float4 v0 = *(const float4*)xp, v1 = *(const float4*)(xp + 4);
    const float4 a0 = *(const float4*)ap, a1 = *(const float4*)(ap + 4);
    const int k = c8 >> 2, g = c8 & 3;
    unsigned short* dst = qp + (size_t)(row >> 4) * 4096 + k * 512 + (row & 15) * 32 + g * 8;
    u16x4 a = { f2bf(v0.x + a0.x), f2bf(v0.y + a0.y), f2bf(v0.z + a0.z), f2bf(v0.w + a0.w) };
    u16x4 b = { f2bf(v1.x + a1.x), f2bf(v1.y + a1.y), f2bf(v1.z + a1.z), f2bf(v1.w + a1.w) };
    *(u16x4*)dst = a;
    *(u16x4*)(dst + 4) = b;
  }
}

// ---------------------------------------------------------------- proj_qkv
// blocks [0,512): K -> Khp[b][h][key][32]
// blocks [512,1024): V -> Vsp sigma store
// blocks [1024,1152): Q -> Qhp[b][h][qrow][32] (head-packed)
__global__ __launch_bounds__(256, 4) void proj_qkv(const unsigned short* __restrict__ kvp,
                                                   const unsigned short* __restrict__ qp,
                                                   const unsigned short* __restrict__ Wqb,
                                                   const unsigned short* __restrict__ Wkb,
                                                   const unsigned short* __restrict__ Wvb,
                                                   unsigned short* __restrict__ Qhp,
                                                   unsigned short* __restrict__ Khp,
                                                   unsigned short* __restrict__ Vsp) {
  const int tid = threadIdx.x;
  const int w = tid >> 6, lane = tid & 63, x = lane & 15, g = lane >> 4;
  const int rg = w & 1, nh = w >> 1;
  const int bx = blockIdx.x;
  if (bx < 1024) {
    const bool isV = bx >= 512;
    const int bk = isV ? bx - 512 : bx;
    const int rbase = bk * 32 + rg * 16;
    const unsigned short* ap = kvp + (size_t)(rbase >> 4) * 4096 + x * 32 + g * 8;
    bf16x8 a[8];
#pragma unroll
    for (int k = 0; k < 8; ++k) a[k] = *(const bf16x8*)(ap + k * 512);
    const unsigned short* Wb = isV ? Wvb : Wkb;
    f32x4 acc[8];
#pragma unroll
    for (int n = 0; n < 8; ++n) acc[n] = (f32x4){0.f, 0.f, 0.f, 0.f};
#pragma unroll
    for (int k = 0; k < 8; ++k)
#pragma unroll
      for (int n0 = 0; n0 < 8; ++n0) {
        const bf16x8 bw = *(const bf16x8*)(Wb + (size_t)(nh * 8 + n0) * 4096 + k * 512 + x * 32 + g * 8);
        acc[n0] = MFMA16(a[k], bw, acc[n0]);
      }
    if (!isV) {
      const int b2 = rbase >> 12, kk0 = (rbase & 4095) + g * 4;
#pragma unroll
      for (int n0 = 0; n0 < 8; ++n0) {
        const int n = nh * 8 + n0, hh = n >> 1, dd = ((n & 1) << 4) + x;
        unsigned short* kp = Khp + (size_t)(b2 * 8 + hh) * 131072;
#pragma unroll
        for (int r = 0; r < 4; ++r)
          kp[(size_t)(kk0 + r) * 32 + dd] = f2bf(acc[n0][r]);
      }
    } else {
      // sigma: key slot m=16c0+4g+r stored at ks=c0&1, i=4*(c0>>1)+r
      const int b2 = rbase >> 12, T = (rbase >> 6) & 63, c0 = (rbase >> 4) & 3;
      const int ks = c0 & 1, ih = (c0 >> 1) << 2;
#pragma unroll
      for (int n0 = 0; n0 < 8; ++n0) {
        const int n = nh * 8 + n0, hh = n >> 1, dh = n & 1;
        u16x4 o = { f2bf(acc[n0][0]), f2bf(acc[n0][1]), f2bf(acc[n0][2]), f2bf(acc[n0][3]) };
        *(u16x4*)(Vsp + (size_t)(b2 * 8 + hh) * 131072 + T * 2048 + ks * 1024 + dh * 512 + g * 128 + x * 8 + ih) = o;
      }
    }
  } else {
    const int bq = bx - 1024;  // 0..127
    const int rbase = bq * 32 + rg * 16;
    const unsigned short* ap = qp + (size_t)(rbase >> 4) * 4096 + x * 32 + g * 8;
    bf16x8 a[8];
#pragma unroll
    for (int k = 0; k < 8; ++k) a[k] = *(const bf16x8*)(ap + k * 512);
    f32x4 acc[8];
#pragma unroll
    for (int n = 0; n < 8; ++n) acc[n] = (f32x4){0.f, 0.f, 0.f, 0.f};
#pragma unroll
    for (int k = 0; k < 8; ++k)
#pragma unroll
      for (int n0 = 0; n0 < 8; ++n0) {
        const bf16x8 bw = *(const bf16x8*)(Wqb + (size_t)(nh * 8 + n0) * 4096 + k * 512 + x * 32 + g * 8);
        acc[n0] = MFMA16(a[k], bw, acc[n0]);
      }
    // head-packed store: Qhp[b][h][qrow][32]
    const int b2 = rbase >> 10, qr0 = (rbase & 1023) + g * 4;
#pragma unroll
    for (int n0 = 0; n0 < 8; ++n0) {
      const int n = nh * 8 + n0, hh = n >> 1, dd = ((n & 1) << 4) + x;
      unsigned short* qpn = Qhp + (size_t)(b2 * 8 + hh) * 32768;
#pragma unroll
      for (int r = 0; r < 4; ++r)
        qpn[(size_t)(qr0 + r) * 32 + dd] = f2bf(acc[n0][r]);
    }
  }
}

// ---------------------------------------------------------------- attn
// 1-D grid of 256*SPLIT blocks, XCD decode h=bid&7 (bid%8 -> XCD round-robin;
// R12 verified FETCH 76->19MB). b=(bid>>3)&3, qt=(bid>>5)&7, z=bid>>8.
// Wave: 32 q-rows (QG=2), groups SEQUENTIAL. Opart written NONTEMPORAL in
// fragment-packed f32 layout (A-frag order for the fused tail). (256,4) cap.
template <int SPLIT, bool PF>
__global__ __launch_bounds__(256, 4) void
attn_fused(const unsigned short* __restrict__ Qhp,
           const unsigned short* __restrict__ Khp,
           const unsigned short* __restrict__ Vsp,
           const void* __restrict__ pos,
           unsigned short* __restrict__ Xo,
           float* __restrict__ Opart,
           float* __restrict__ lpart) {
  const int tid = threadIdx.x;
  const int w = tid >> 6, lane = tid & 63, x = lane & 15, g = lane >> 4;
  const int bid = blockIdx.x;
  const int h = bid & 7, b = (bid >> 3) & 3, qt = (bid >> 5) & 7, z = bid >> 8;
  const int qrow0 = qt * 128 + w * 32;
  const int NT = 64 / SPLIT;

  const unsigned short* Qpl = Qhp + (size_t)(b * 8 + h) * 32768;
  const bf16x8 aq0 = *(const bf16x8*)(Qpl + (size_t)(qrow0 + x) * 32 + g * 8);
  const bf16x8 aq1 = *(const bf16x8*)(Qpl + (size_t)(qrow0 + 16 + x) * 32 + g * 8);
  const unsigned short* Kpl = Khp + (size_t)(b * 8 + h) * 131072 + x * 32 + g * 8;
  const unsigned short* Vpl = Vsp + (size_t)(b * 8 + h) * 131072 + g * 128 + x * 8;
  // PF: bf16 pre-scaled bias, fragment-packed. !PF: raw fp32 [h][q][zkey].
  const unsigned short* pq0 = PF ? (const unsigned short*)pos + (size_t)((h << 6) + (qt << 3) + (w << 1)) * 16384 : nullptr;
  const unsigned short* pq1 = PF ? pq0 + 16384 : nullptr;
  const float* pr0 = PF ? nullptr : (const float*)pos + (size_t)((h << 10) + qrow0 + x) * 1024;
  const float* pr1 = PF ? nullptr : (const float*)pos + (size_t)((h << 10) + qrow0 + 16 + x) * 1024;
  const f32x4 zc = {0.f, 0.f, 0.f, 0.f};

  f32x4 o00 = zc, o01 = zc, o10 = zc, o11 = zc;
  float ls0 = 0.f, ls1 = 0.f;

  bf16x8 ka[4], va[4];
  // preload tile t = z
#pragma unroll
  for (int c = 0; c < 4; ++c)
    ka[c] = *(const bf16x8*)(Kpl + (size_t)((z << 6) + c * 16) * 32);
#pragma unroll
  for (int j = 0; j < 4; ++j)
    va[j] = *(const bf16x8*)(Vpl + (z << 11) + (j << 9));

// One q-group: QK -> [bias] -> exp2/lsum -> pack -> PV. s[4]/pa transient.
#define GROUP(AQ, PQ, PR, LS, OA, OB, T, BIAS)                                               \
  do {                                                                                       \
    f32x4 s[4];                                                                              \
    _Pragma("unroll")                                                                        \
    for (int c = 0; c < 4; ++c) s[c] = MFMA16(ka[c], AQ, zc);                                \
    if (BIAS) {                                                                              \
      if (PF) {                                                                              \
        _Pragma("unroll")                                                                    \
        for (int c = 0; c < 4; ++c) {                                                        \
          const u16x4 p = *(const u16x4*)(PQ + ((T) << 10) + (c << 8) + (x << 4) + (g << 2)); \
          s[c][0] += bf2f(p[0]); s[c][1] += bf2f(p[1]);                                      \
          s[c][2] += bf2f(p[2]); s[c][3] += bf2f(p[3]);                                      \
        }                                                                                    \
      } else {                                                                               \
        const float LOG2E = 1.4426950408889634f;                                             \
        _Pragma("unroll")                                                                    \
        for (int c = 0; c < 4; ++c) {                                                        \
          const float4 p = *(const float4*)(PR + ((T) << 6) + c * 16 + g * 4);               \
          s[c][0] = fmaf(p.x, LOG2E, s[c][0]); s[c][1] = fmaf(p.y, LOG2E, s[c][1]);          \
          s[c][2] = fmaf(p.z, LOG2E, s[c][2]); s[c][3] = fmaf(p.w, LOG2E, s[c][3]);          \
        }                                                                                    \
      }                                                                                      \
    }                                                                                        \
    _Pragma("unroll")                                                                        \
    for (int c = 0; c < 4; ++c)                                                              \
      _Pragma("unroll")                                                                      \
      for (int r = 0; r < 4; ++r) {                                                          \
        s[c][r] = __builtin_amdgcn_exp2f(s[c][r]); LS += s[c][r];                            \
      }                                                                                      \
    bf16x8 pa0, pa1;                                                                         \
    _Pragma("unroll")                                                                        \
    for (int r = 0; r < 4; ++r) {                                                            \
      pa0[r] = (short)f2bf(s[0][r]); pa0[4 + r] = (short)f2bf(s[2][r]);                      \
      pa1[r] = (short)f2bf(s[1][r]); pa1[4 + r] = (short)f2bf(s[3][r]);                      \
    }                                                                                        \
    OA = MFMA16(pa0, va[0], OA); OB = MFMA16(pa0, va[1], OB);                                \
    OA = MFMA16(pa1, va[2], OA); OB = MFMA16(pa1, va[3], OB);                                \
  } while (0)

#define TILE(T, BIAS)                                                                        \
  do {                                                                                       \
    const int tp = ((T) + SPLIT <= 63) ? (T) + SPLIT : (T);                                  \
    GROUP(aq0, pq0, pr0, ls0, o00, o01, T, BIAS);                                            \
    GROUP(aq1, pq1, pr1, ls1, o10, o11, T, BIAS);                                            \
    _Pragma("unroll")                                                                        \
    for (int c = 0; c < 4; ++c)  /* reuse-prefetch K for tile tp */                          \
      ka[c] = *(const bf16x8*)(Kpl + (size_t)((tp << 6) + c * 16) * 32);                     \
    _Pragma("unroll")                                                                        \
    for (int j = 0; j < 4; ++j)  /* reuse-prefetch V for tile tp */                          \
      va[j] = *(const bf16x8*)(Vpl + (tp << 11) + (j << 9));                                 \
  } while (0)

  const int nb = 16 / SPLIT;  // biased iterations
  int t = z;
  for (int i = 0; i < nb; ++i) { TILE(t, true);  t += SPLIT; }
  for (int i = nb; i < NT; ++i) { TILE(t, false); t += SPLIT; }
#undef TILE
#undef GROUP

  ls0 += __shfl_xor(ls0, 16); ls0 += __shfl_xor(ls0, 32);
  ls1 += __shfl_xor(ls1, 16); ls1 += __shfl_xor(ls1, 32);

  if (SPLIT == 1) {
    // fragment-packed X write (matches proj_out's packed A reads)
    const float inv0 = 1.f / ls0, inv1 = 1.f / ls1;
    const int rowblk = (b << 6) + (qt << 3) + (w << 1);
#pragma unroll
    for (int r = 0; r < 4; ++r) {
      const float ir0 = __shfl(inv0, g * 4 + r, 64);
      const float ir1 = __shfl(inv1, g * 4 + r, 64);
      unsigned short* d0 = Xo + (size_t)rowblk * 4096 + h * 512 + (g * 4 + r) * 32;
      unsigned short* d1 = Xo + (size_t)(rowblk + 1) * 4096 + h * 512 + (g * 4 + r) * 32;
      d0[x] = f2bf(o00[r] * ir0);
      d0[16 + x] = f2bf(o01[r] * ir0);
      d1[x] = f2bf(o10[r] * ir1);
      d1[16 + x] = f2bf(o11[r] * ir1);
    }
  } else {
    if (g == 0) {
      __builtin_nontemporal_store(ls0, &lpart[(size_t)z * 32768 + ((b << 10) + qrow0 + x) * 8 + h]);
      __builtin_nontemporal_store(ls1, &lpart[(size_t)z * 32768 + ((b << 10) + qrow0 + 16 + x) * 8 + h]);
    }
    // fragment-packed f32 partials: row (g*4+r) of rowblk, cols h*32 + {x, 16+x}
    const int rowblk = (b << 6) + (qt << 3) + (w << 1);
#pragma unroll
    for (int r = 0; r < 4; ++r) {
      float* b0 = Opart + (size_t)z * 1048576 + (size_t)rowblk * 4096 + h * 512 + (g * 4 + r) * 32;
      float* b1 = b0 + 4096;
      __builtin_nontemporal_store(o00[r], b0 + x);
      __builtin_nontemporal_store(o01[r], b0 + 16 + x);
      __builtin_nontemporal_store(o10[r], b1 + x);
      __builtin_nontemporal_store(o11[r], b1 + 16 + x);
    }
  }
}

// ---------------------------------------------------------------- proj_out_c
// Fused combine + out-projection. Grid 1024: bid = rowblk*4 + colq; block =
// 16 rows x 64 cols; wave w covers col group n = colq*4 + w. Compile-time
// SPLIT -> z-loops fully unrolled (32-64 independent loads in flight).
template <int SPLIT>
__global__ __launch_bounds__(256) void proj_out_c(const float* __restrict__ Opart,
                                                  const float* __restrict__ lpart,
                                                  const unsigned short* __restrict__ Wb,
                                                  const float* __restrict__ bias,
                                                  float* __restrict__ out) {
  const int tid = threadIdx.x;
  const int w = tid >> 6, lane = tid & 63, x = lane & 15, g = lane >> 4;
  const int blk = blockIdx.x >> 2, cq = blockIdx.x & 3;
  const int rbase = blk << 4;
  const int n = (cq << 2) + w;  // 16-col output group, 0..15

  // denominators for row rbase+x, all 8 heads (unrolled SPLIT)
  float l[8];
#pragma unroll
  for (int k = 0; k < 8; ++k) l[k] = 0.f;
#pragma unroll
  for (int zz = 0; zz < SPLIT; ++zz) {
    const float* lp = lpart + (size_t)zz * 32768 + (size_t)(rbase + x) * 8;
    const float4 l0 = *(const float4*)lp, l1 = *(const float4*)(lp + 4);
    l[0] += l0.x; l[1] += l0.y; l[2] += l0.z; l[3] += l0.w;
    l[4] += l1.x; l[5] += l1.y; l[6] += l1.z; l[7] += l1.w;
  }
#pragma unroll
  for (int k = 0; k < 8; ++k) l[k] = 1.f / l[k];

  f32x4 acc = (f32x4){0.f, 0.f, 0.f, 0.f};
#pragma unroll
  for (int k = 0; k < 8; ++k) {
    float s[8];
#pragma unroll
    for (int i = 0; i < 8; ++i) s[i] = 0.f;
#pragma unroll
    for (int zz = 0; zz < SPLIT; ++zz) {
      const float* op = Opart + (size_t)zz * 1048576 + (size_t)blk * 4096 + k * 512 + x * 32 + g * 8;
      const float4 v0 = *(const float4*)op, v1 = *(const float4*)(op + 4);
      s[0] += v0.x; s[1] += v0.y; s[2] += v0.z; s[3] += v0.w;
      s[4] += v1.x; s[5] += v1.y; s[6] += v1.z; s[7] += v1.w;
    }
    bf16x8 av;
#pragma unroll
    for (int i = 0; i < 8; ++i) av[i] = (short)f2bf(s[i] * l[k]);
    const bf16x8 bw = *(const bf16x8*)(Wb + (size_t)n * 4096 + k * 512 + x * 32 + g * 8);
    acc = MFMA16(av, bw, acc);
  }
  const float bv = bias[n * 16 + x];
#pragma unroll
  for (int r = 0; r < 4; ++r)
    out[(size_t)(rbase + g * 4 + r) * 256 + n * 16 + x] = acc[r] + bv;
}

// ---------------------------------------------------------------- proj_out (split==1 fallback)
__global__ __launch_bounds__(256) void proj_out(const unsigned short* __restrict__ Xp,
                                                const unsigned short* __restrict__ Wb,
                                                const float* __restrict__ bias,
                                                float* __restrict__ out) {
  const int tid = threadIdx.x;
  const int w = tid >> 6, lane = tid & 63, x = lane & 15, g = lane >> 4;
  const int rbase = blockIdx.x << 4;
  const int cb = w << 6;
  const unsigned short* ap = Xp + (size_t)blockIdx.x * 4096 + x * 32 + g * 8;
  bf16x8 a[8];
#pragma unroll
  for (int k = 0; k < 8; ++k) a[k] = *(const bf16x8*)(ap + k * 512);
  f32x4 acc[4];
#pragma unroll
  for (int n = 0; n < 4; ++n) acc[n] = (f32x4){0.f, 0.f, 0.f, 0.f};
#pragma unroll
  for (int k = 0; k < 8; ++k)
#pragma unroll
    for (int n = 0; n < 4; ++n) {
      const bf16x8 bw = *(const bf16x8*)(Wb + (size_t)((w << 2) + n) * 4096 + k * 512 + x * 32 + g * 8);
      acc[n] = MFMA16(a[k], bw, acc[n]);
    }
#pragma unroll
  for (int n = 0; n < 4; ++n) {
    const float bv = bias[cb + n * 16 + x];
#pragma unroll
    for (int r = 0; r < 4; ++r)
      out[(size_t)(rbase + g * 4 + r) * 256 + cb + n * 16 + x] = acc[n][r] + bv;
  }
}

// ---------------------------------------------------------------- launch
extern "C" void kernel_launch(void* const* d_in, const int* in_sizes, int n_in,
                              void* d_out, int out_size, void* d_ws, size_t ws_size,
                              hipStream_t stream) {
  const float* q        = (const float*)d_in[0];
  const float* kv       = (const float*)d_in[1];
  const float* q_ape    = (const float*)d_in[2];
  const float* k_ape    = (const float*)d_in[3];
  const float* attn_pos = (const float*)d_in[4];
  const float* Wq       = (const float*)d_in[5];
  const float* Wk       = (const float*)d_in[6];
  const float* Wv       = (const float*)d_in[7];
  const float* Wp       = (const float*)d_in[8];
  const float* bp       = (const float*)d_in[9];
  float* out = (float*)d_out;

  unsigned short* wsb = (unsigned short*)d_ws;
  unsigned short* Wqb = wsb;                 // 4 x 65536 shorts (fragment-packed)
  unsigned short* Wkb = wsb + 65536;
  unsigned short* Wvb = wsb + 131072;
  unsigned short* Wpb = wsb + 196608;
  unsigned short* Qhp = wsb + 262144;        // [4][8][1024][32] head-packed
  unsigned short* Khp = wsb + 1310720;       // [4][8][4096][32]
  unsigned short* Vsp = wsb + 5505024;       // sigma-permuted V
  unsigned short* Xws = wsb + 9699328;       // fragment-packed X (split==1 path)
  unsigned short* kvp = wsb + 10747904;      // packed kv+ape (8MB)
  unsigned short* qp  = wsb + 14942208;      // packed q+ape  (2MB)

  const size_t L0  = 31981568ull;            // bytes of everything above
  const size_t PFB = 16777216ull;            // pf bf16 bytes
  const size_t PS  = 4325376ull;             // per-split Opart+lpart bytes
  int split; bool havepf;
  if      (ws_size >= L0 + PFB + 4 * PS) { split = 4; havepf = true; }
  else if (ws_size >= L0 + 4 * PS)       { split = 4; havepf = false; }
  else if (ws_size >= L0 + 2 * PS)       { split = 2; havepf = false; }
  else                                   { split = 1; havepf = false; }
  unsigned short* pfb = (unsigned short*)((char*)d_ws + L0);
  float* Opart = (float*)((char*)d_ws + L0 + (havepf ? PFB : 0));
  float* lpart = Opart + (size_t)split * 1048576;

  const int posBlocks = havepf ? 8192 : 0;
  prep_all<<<posBlocks + 128 + 2048 + 512, 256, 0, stream>>>(
      Wq, Wk, Wv, Wp, attn_pos, q, kv, q_ape, k_ape, wsb, pfb, kvp, qp, posBlocks);
  proj_qkv<<<1152, 256, 0, stream>>>(kvp, qp, Wqb, Wkb, Wvb, Qhp, Khp, Vsp);
  if (havepf)
    attn_fused<4, true><<<1024, 256, 0, stream>>>(Qhp, Khp, Vsp, pfb, Xws, Opart, lpart);
  else if (split == 4)
    attn_fused<4, false><<<1024, 256, 0, stream>>>(Qhp, Khp, Vsp, attn_pos, Xws, Opart, lpart);
  else if (split == 2)
    attn_fused<2, false><<<512, 256, 0, stream>>>(Qhp, Khp, Vsp, attn_pos, Xws, Opart, lpart);
  else
    attn_fused<1, false><<<256, 256, 0, stream>>>(Qhp, Khp, Vsp, attn_pos, Xws, Opart, lpart);
  if (split == 4)
    proj_out_c<4><<<1024, 256, 0, stream>>>(Opart, lpart, Wpb, bp, out);
  else if (split == 2)
    proj_out_c<2><<<1024, 256, 0, stream>>>(Opart, lpart, Wpb, bp, out);
  else
    proj_out<<<256, 256, 0, stream>>>(Xws, Wpb, bp, out);
}

// Round 18
// 88.496 us; speedup vs baseline: 1.3614x; 1.2645x over previous
//
#include <hip/hip_runtime.h>

// Fused cross-attention, MI355X gfx950. B=4, LQ=1024, LKV=4096, C=256, H=8, d=32, Z=1024.
//
// R18 = exact revert to R15 (best measured: 88.4us total, attn 39.4us).
// R16/R17's tail fusions both regressed (proj_out_c re-reads each HBM-resident
// partial row-block 4x with a serial per-k chain); R15's split kernels stream
// partials once, coalesced. Config: attn split=4/QG=2/seq-groups/XCD-swizzle/
// nt partial stores; combine -> packed-X; proj_out packed-A reads.
//
//   prep_all: W pack + pos pack (bf16*log2e) + kv pack + q pack (elementwise)
//   proj_qkv: Khp[b][h][key][32]; Vsp (sigma-permuted); Qhp[b][h][qrow][32]
//   attn:     fixed-max (M=0) flash attention, KV-split 4, LDS-free, QG=2
//   combine:  sum partials, normalize -> Xp (fragment-packed bf16)
//   proj_out: out = fp32(Xp @ Wp^T + bp), packed A reads
//
// mfma_f32_16x16x32_bf16 layouts (m89-verified):
//   A: row=l&15, k=(l>>4)*8+i ; B: col=l&15, k=(l>>4)*8+i ; C: col=l&15, row=(l>>4)*4+r

typedef __attribute__((ext_vector_type(8))) short bf16x8;
typedef __attribute__((ext_vector_type(4))) float f32x4;
typedef __attribute__((ext_vector_type(4))) unsigned short u16x4;

#define MFMA16(a, b, c) __builtin_amdgcn_mfma_f32_16x16x32_bf16((a), (b), (c), 0, 0, 0)

__device__ __forceinline__ unsigned short f2bf(float f) {
  return __builtin_bit_cast(unsigned short, static_cast<__bf16>(f));  // RNE
}
__device__ __forceinline__ float bf2f(unsigned short u) {
  return __builtin_bit_cast(float, ((unsigned)u) << 16);
}

// ---------------------------------------------------------------- prep_all
__global__ __launch_bounds__(256) void prep_all(const float* __restrict__ Wq,
                                                const float* __restrict__ Wk,
                                                const float* __restrict__ Wv,
                                                const float* __restrict__ Wp,
                                                const float* __restrict__ pos,
                                                const float* __restrict__ Xq,
                                                const float* __restrict__ Xkv,
                                                const float* __restrict__ q_ape,
                                                const float* __restrict__ k_ape,
                                                unsigned short* __restrict__ wout,
                                                unsigned short* __restrict__ pfb,
                                                unsigned short* __restrict__ kvp,
                                                unsigned short* __restrict__ qp,
                                                int posBlocks) {
  int bx = blockIdx.x;
  if (bx < posBlocks) {
    const int s4 = bx * 256 + threadIdx.x;  // 2,097,152 threads, 4 floats each
    const int zk4 = s4 & 255, q = (s4 >> 8) & 1023, h = s4 >> 18;
    const float4 v = *(const float4*)(pos + ((size_t)s4 << 2));
    const int kt = zk4 >> 4, c = (zk4 >> 2) & 3, g = zk4 & 3;
    const float L = 1.4426950408889634f;
    u16x4 o = { f2bf(v.x * L), f2bf(v.y * L), f2bf(v.z * L), f2bf(v.w * L) };
    *(u16x4*)(pfb + (size_t)((h << 6) + (q >> 4)) * 16384 + ((kt << 2) + c) * 256 + ((q & 15) << 4) + (g << 2)) = o;
    return;
  }
  bx -= posBlocks;
  if (bx < 128) {
    const int idx = bx * 256 + threadIdx.x;  // 32768 threads
    const int which = idx >> 13, rem = idx & 8191;
    const int o = rem >> 5, colb = (rem & 31) << 3;
    const float* src = (which == 0) ? Wq : (which == 1) ? Wk : (which == 2) ? Wv : Wp;
    float4 v0 = *(const float4*)(src + (size_t)o * 256 + colb);
    float4 v1 = *(const float4*)(src + (size_t)o * 256 + colb + 4);
    if (which == 0) {  // fold softmax scale and log2(e) into Wq
      const float qs = 0.17677669529663687f * 1.4426950408889634f;
      v0.x *= qs; v0.y *= qs; v0.z *= qs; v0.w *= qs;
      v1.x *= qs; v1.y *= qs; v1.z *= qs; v1.w *= qs;
    }
    const int n = o >> 4, x = o & 15, k = colb >> 5, g = (colb & 31) >> 3;
    unsigned short* dst = wout + (which << 16) + n * 4096 + k * 512 + x * 32 + g * 8;
    u16x4 a = { f2bf(v0.x), f2bf(v0.y), f2bf(v0.z), f2bf(v0.w) };
    u16x4 b = { f2bf(v1.x), f2bf(v1.y), f2bf(v1.z), f2bf(v1.w) };
    *(u16x4*)dst = a;
    *(u16x4*)(dst + 4) = b;
    return;
  }
  bx -= 128;
  if (bx < 2048) {
    const int idx = bx * 256 + threadIdx.x;  // 524,288 threads: 16384 rows x 32 col-chunks
    const int row = idx >> 5, c8 = idx & 31;
    const int col = c8 << 3, lq = row & 4095;
    const float* xp = Xkv + (size_t)row * 256 + col;
    float4 v0 = *(const float4*)xp, v1 = *(const float4*)(xp + 4);
    if (lq >= 1024) {  // k_ape covers kv rows [Z, LKV)
      const float* ap = k_ape + (size_t)(lq - 1024) * 256 + col;
      const float4 a0 = *(const float4*)ap, a1 = *(const float4*)(ap + 4);
      v0.x += a0.x; v0.y += a0.y; v0.z += a0.z; v0.w += a0.w;
      v1.x += a1.x; v1.y += a1.y; v1.z += a1.z; v1.w += a1.w;
    }
    const int k = c8 >> 2, g = c8 & 3;
    unsigned short* dst = kvp + (size_t)(row >> 4) * 4096 + k * 512 + (row & 15) * 32 + g * 8;
    u16x4 a = { f2bf(v0.x), f2bf(v0.y), f2bf(v0.z), f2bf(v0.w) };
    u16x4 b = { f2bf(v1.x), f2bf(v1.y), f2bf(v1.z), f2bf(v1.w) };
    *(u16x4*)dst = a;
    *(u16x4*)(dst + 4) = b;
    return;
  }
  bx -= 2048;
  {
    const int idx = bx * 256 + threadIdx.x;  // 131,072 threads: 4096 rows x 32 chunks
    const int row = idx >> 5, c8 = idx & 31;
    const int col = c8 << 3, arow = row & 1023;
    const float* xp = Xq + (size_t)row * 256 + col;
    const float* ap = q_ape + (size_t)arow * 256 + col;
    const float4 v0 = *(const float4*)xp, v1 = *(const float4*)(xp + 4);
    const float4 a0 = *(const float4*)ap, a1 = *(const float4*)(ap + 4);
    const int k = c8 >> 2, g = c8 & 3;
    unsigned short* dst = qp + (size_t)(row >> 4) * 4096 + k * 512 + (row & 15) * 32 + g * 8;
    u16x4 a = { f2bf(v0.x + a0.x), f2bf(v0.y + a0.y), f2bf(v0.z + a0.z), f2bf(v0.w + a0.w) };
    u16x4 b = { f2bf(v1.x + a1.x), f2bf(v1.y + a1.y), f2bf(v1.z + a1.z), f2bf(v1.w + a1.w) };
    *(u16x4*)dst = a;
    *(u16x4*)(dst + 4) = b;
  }
}

// ---------------------------------------------------------------- proj_qkv
// blocks [0,512): K -> Khp[b][h][key][32]
// blocks [512,1024): V -> Vsp sigma store
// blocks [1024,1152): Q -> Qhp[b][h][qrow][32] (head-packed)
__global__ __launch_bounds__(256, 4) void proj_qkv(const unsigned short* __restrict__ kvp,
                                                   const unsigned short* __restrict__ qp,
                                                   const unsigned short* __restrict__ Wqb,
                                                   const unsigned short* __restrict__ Wkb,
                                                   const unsigned short* __restrict__ Wvb,
                                                   unsigned short* __restrict__ Qhp,
                                                   unsigned short* __restrict__ Khp,
                                                   unsigned short* __restrict__ Vsp) {
  const int tid = threadIdx.x;
  const int w = tid >> 6, lane = tid & 63, x = lane & 15, g = lane >> 4;
  const int rg = w & 1, nh = w >> 1;
  const int bx = blockIdx.x;
  if (bx < 1024) {
    const bool isV = bx >= 512;
    const int bk = isV ? bx - 512 : bx;
    const int rbase = bk * 32 + rg * 16;
    const unsigned short* ap = kvp + (size_t)(rbase >> 4) * 4096 + x * 32 + g * 8;
    bf16x8 a[8];
#pragma unroll
    for (int k = 0; k < 8; ++k) a[k] = *(const bf16x8*)(ap + k * 512);
    const unsigned short* Wb = isV ? Wvb : Wkb;
    f32x4 acc[8];
#pragma unroll
    for (int n = 0; n < 8; ++n) acc[n] = (f32x4){0.f, 0.f, 0.f, 0.f};
#pragma unroll
    for (int k = 0; k < 8; ++k)
#pragma unroll
      for (int n0 = 0; n0 < 8; ++n0) {
        const bf16x8 bw = *(const bf16x8*)(Wb + (size_t)(nh * 8 + n0) * 4096 + k * 512 + x * 32 + g * 8);
        acc[n0] = MFMA16(a[k], bw, acc[n0]);
      }
    if (!isV) {
      const int b2 = rbase >> 12, kk0 = (rbase & 4095) + g * 4;
#pragma unroll
      for (int n0 = 0; n0 < 8; ++n0) {
        const int n = nh * 8 + n0, hh = n >> 1, dd = ((n & 1) << 4) + x;
        unsigned short* kp = Khp + (size_t)(b2 * 8 + hh) * 131072;
#pragma unroll
        for (int r = 0; r < 4; ++r)
          kp[(size_t)(kk0 + r) * 32 + dd] = f2bf(acc[n0][r]);
      }
    } else {
      // sigma: key slot m=16c0+4g+r stored at ks=c0&1, i=4*(c0>>1)+r
      const int b2 = rbase >> 12, T = (rbase >> 6) & 63, c0 = (rbase >> 4) & 3;
      const int ks = c0 & 1, ih = (c0 >> 1) << 2;
#pragma unroll
      for (int n0 = 0; n0 < 8; ++n0) {
        const int n = nh * 8 + n0, hh = n >> 1, dh = n & 1;
        u16x4 o = { f2bf(acc[n0][0]), f2bf(acc[n0][1]), f2bf(acc[n0][2]), f2bf(acc[n0][3]) };
        *(u16x4*)(Vsp + (size_t)(b2 * 8 + hh) * 131072 + T * 2048 + ks * 1024 + dh * 512 + g * 128 + x * 8 + ih) = o;
      }
    }
  } else {
    const int bq = bx - 1024;  // 0..127
    const int rbase = bq * 32 + rg * 16;
    const unsigned short* ap = qp + (size_t)(rbase >> 4) * 4096 + x * 32 + g * 8;
    bf16x8 a[8];
#pragma unroll
    for (int k = 0; k < 8; ++k) a[k] = *(const bf16x8*)(ap + k * 512);
    f32x4 acc[8];
#pragma unroll
    for (int n = 0; n < 8; ++n) acc[n] = (f32x4){0.f, 0.f, 0.f, 0.f};
#pragma unroll
    for (int k = 0; k < 8; ++k)
#pragma unroll
      for (int n0 = 0; n0 < 8; ++n0) {
        const bf16x8 bw = *(const bf16x8*)(Wqb + (size_t)(nh * 8 + n0) * 4096 + k * 512 + x * 32 + g * 8);
        acc[n0] = MFMA16(a[k], bw, acc[n0]);
      }
    // head-packed store: Qhp[b][h][qrow][32]
    const int b2 = rbase >> 10, qr0 = (rbase & 1023) + g * 4;
#pragma unroll
    for (int n0 = 0; n0 < 8; ++n0) {
      const int n = nh * 8 + n0, hh = n >> 1, dd = ((n & 1) << 4) + x;
      unsigned short* qpn = Qhp + (size_t)(b2 * 8 + hh) * 32768;
#pragma unroll
      for (int r = 0; r < 4; ++r)
        qpn[(size_t)(qr0 + r) * 32 + dd] = f2bf(acc[n0][r]);
    }
  }
}

// ---------------------------------------------------------------- attn
// 1-D grid of 256*SPLIT blocks, XCD decode h=bid&7 (bid%8 -> XCD round-robin;
// R12 verified FETCH 76->19MB). b=(bid>>3)&3, qt=(bid>>5)&7, z=bid>>8.
// Wave: 32 q-rows (QG=2), groups SEQUENTIAL (one s[4] transient at a time).
// Opart/lpart stores NONTEMPORAL (R14: cached partial writes evict the K/V+pf
// L2 working set). LDS-free. (256,4) cap — (256,8) forces spill (R9).
template <int SPLIT, bool PF>
__global__ __launch_bounds__(256, 4) void
attn_fused(const unsigned short* __restrict__ Qhp,
           const unsigned short* __restrict__ Khp,
           const unsigned short* __restrict__ Vsp,
           const void* __restrict__ pos,
           unsigned short* __restrict__ Xo,
           float* __restrict__ Opart,
           float* __restrict__ lpart) {
  const int tid = threadIdx.x;
  const int w = tid >> 6, lane = tid & 63, x = lane & 15, g = lane >> 4;
  const int bid = blockIdx.x;
  const int h = bid & 7, b = (bid >> 3) & 3, qt = (bid >> 5) & 7, z = bid >> 8;
  const int qrow0 = qt * 128 + w * 32;
  const int NT = 64 / SPLIT;

  const unsigned short* Qpl = Qhp + (size_t)(b * 8 + h) * 32768;
  const bf16x8 aq0 = *(const bf16x8*)(Qpl + (size_t)(qrow0 + x) * 32 + g * 8);
  const bf16x8 aq1 = *(const bf16x8*)(Qpl + (size_t)(qrow0 + 16 + x) * 32 + g * 8);
  const unsigned short* Kpl = Khp + (size_t)(b * 8 + h) * 131072 + x * 32 + g * 8;
  const unsigned short* Vpl = Vsp + (size_t)(b * 8 + h) * 131072 + g * 128 + x * 8;
  // PF: bf16 pre-scaled bias, fragment-packed. !PF: raw fp32 [h][q][zkey].
  const unsigned short* pq0 = PF ? (const unsigned short*)pos + (size_t)((h << 6) + (qt << 3) + (w << 1)) * 16384 : nullptr;
  const unsigned short* pq1 = PF ? pq0 + 16384 : nullptr;
  const float* pr0 = PF ? nullptr : (const float*)pos + (size_t)((h << 10) + qrow0 + x) * 1024;
  const float* pr1 = PF ? nullptr : (const float*)pos + (size_t)((h << 10) + qrow0 + 16 + x) * 1024;
  const f32x4 zc = {0.f, 0.f, 0.f, 0.f};

  f32x4 o00 = zc, o01 = zc, o10 = zc, o11 = zc;
  float ls0 = 0.f, ls1 = 0.f;

  bf16x8 ka[4], va[4];
  // preload tile t = z
#pragma unroll
  for (int c = 0; c < 4; ++c)
    ka[c] = *(const bf16x8*)(Kpl + (size_t)((z << 6) + c * 16) * 32);
#pragma unroll
  for (int j = 0; j < 4; ++j)
    va[j] = *(const bf16x8*)(Vpl + (z << 11) + (j << 9));

// One q-group: QK -> [bias] -> exp2/lsum -> pack -> PV. s[4]/pa transient.
#define GROUP(AQ, PQ, PR, LS, OA, OB, T, BIAS)                                               \
  do {                                                                                       \
    f32x4 s[4];                                                                              \
    _Pragma("unroll")                                                                        \
    for (int c = 0; c < 4; ++c) s[c] = MFMA16(ka[c], AQ, zc);                                \
    if (BIAS) {                                                                              \
      if (PF) {                                                                              \
        _Pragma("unroll")                                                                    \
        for (int c = 0; c < 4; ++c) {                                                        \
          const u16x4 p = *(const u16x4*)(PQ + ((T) << 10) + (c << 8) + (x << 4) + (g << 2)); \
          s[c][0] += bf2f(p[0]); s[c][1] += bf2f(p[1]);                                      \
          s[c][2] += bf2f(p[2]); s[c][3] += bf2f(p[3]);                                      \
        }                                                                                    \
      } else {                                                                               \
        const float LOG2E = 1.4426950408889634f;                                             \
        _Pragma("unroll")                                                                    \
        for (int c = 0; c < 4; ++c) {                                                        \
          const float4 p = *(const float4*)(PR + ((T) << 6) + c * 16 + g * 4);               \
          s[c][0] = fmaf(p.x, LOG2E, s[c][0]); s[c][1] = fmaf(p.y, LOG2E, s[c][1]);          \
          s[c][2] = fmaf(p.z, LOG2E, s[c][2]); s[c][3] = fmaf(p.w, LOG2E, s[c][3]);          \
        }                                                                                    \
      }                                                                                      \
    }                                                                                        \
    _Pragma("unroll")                                                                        \
    for (int c = 0; c < 4; ++c)                                                              \
      _Pragma("unroll")                                                                      \
      for (int r = 0; r < 4; ++r) {                                                          \
        s[c][r] = __builtin_amdgcn_exp2f(s[c][r]); LS += s[c][r];                            \
      }                                                                                      \
    bf16x8 pa0, pa1;                                                                         \
    _Pragma("unroll")                                                                        \
    for (int r = 0; r < 4; ++r) {                                                            \
      pa0[r] = (short)f2bf(s[0][r]); pa0[4 + r] = (short)f2bf(s[2][r]);                      \
      pa1[r] = (short)f2bf(s[1][r]); pa1[4 + r] = (short)f2bf(s[3][r]);                      \
    }                                                                                        \
    OA = MFMA16(pa0, va[0], OA); OB = MFMA16(pa0, va[1], OB);                                \
    OA = MFMA16(pa1, va[2], OA); OB = MFMA16(pa1, va[3], OB);                                \
  } while (0)

#define TILE(T, BIAS)                                                                        \
  do {                                                                                       \
    const int tp = ((T) + SPLIT <= 63) ? (T) + SPLIT : (T);                                  \
    GROUP(aq0, pq0, pr0, ls0, o00, o01, T, BIAS);                                            \
    GROUP(aq1, pq1, pr1, ls1, o10, o11, T, BIAS);                                            \
    _Pragma("unroll")                                                                        \
    for (int c = 0; c < 4; ++c)  /* reuse-prefetch K for tile tp */                          \
      ka[c] = *(const bf16x8*)(Kpl + (size_t)((tp << 6) + c * 16) * 32);                     \
    _Pragma("unroll")                                                                        \
    for (int j = 0; j < 4; ++j)  /* reuse-prefetch V for tile tp */                          \
      va[j] = *(const bf16x8*)(Vpl + (tp << 11) + (j << 9));                                 \
  } while (0)

  const int nb = 16 / SPLIT;  // biased iterations
  int t = z;
  for (int i = 0; i < nb; ++i) { TILE(t, true);  t += SPLIT; }
  for (int i = nb; i < NT; ++i) { TILE(t, false); t += SPLIT; }
#undef TILE
#undef GROUP

  ls0 += __shfl_xor(ls0, 16); ls0 += __shfl_xor(ls0, 32);
  ls1 += __shfl_xor(ls1, 16); ls1 += __shfl_xor(ls1, 32);

  if (SPLIT == 1) {
    // fragment-packed X write (matches proj_out's packed A reads)
    const float inv0 = 1.f / ls0, inv1 = 1.f / ls1;
    const int rowblk = (b << 6) + (qt << 3) + (w << 1);
#pragma unroll
    for (int r = 0; r < 4; ++r) {
      const float ir0 = __shfl(inv0, g * 4 + r, 64);
      const float ir1 = __shfl(inv1, g * 4 + r, 64);
      unsigned short* d0 = Xo + (size_t)rowblk * 4096 + h * 512 + (g * 4 + r) * 32;
      unsigned short* d1 = Xo + (size_t)(rowblk + 1) * 4096 + h * 512 + (g * 4 + r) * 32;
      d0[x] = f2bf(o00[r] * ir0);
      d0[16 + x] = f2bf(o01[r] * ir0);
      d1[x] = f2bf(o10[r] * ir1);
      d1[16 + x] = f2bf(o11[r] * ir1);
    }
  } else {
    if (g == 0) {
      __builtin_nontemporal_store(ls0, &lpart[(size_t)z * 32768 + ((b << 10) + qrow0 + x) * 8 + h]);
      __builtin_nontemporal_store(ls1, &lpart[(size_t)z * 32768 + ((b << 10) + qrow0 + 16 + x) * 8 + h]);
    }
#pragma unroll
    for (int r = 0; r < 4; ++r) {
      const size_t orow0 = (size_t)z * 1048576 + (size_t)((b << 10) + qrow0 + g * 4 + r) * 256 + h * 32;
      const size_t orow1 = (size_t)z * 1048576 + (size_t)((b << 10) + qrow0 + 16 + g * 4 + r) * 256 + h * 32;
      __builtin_nontemporal_store(o00[r], &Opart[orow0 + x]);
      __builtin_nontemporal_store(o01[r], &Opart[orow0 + 16 + x]);
      __builtin_nontemporal_store(o10[r], &Opart[orow1 + x]);
      __builtin_nontemporal_store(o11[r], &Opart[orow1 + 16 + x]);
    }
  }
}

// ---------------------------------------------------------------- combine
// Writes Xp in fragment-packed layout: off = (row>>4)*4096 + (col>>5)*512 +
// (row&15)*32 + ((col>>3)&3)*8 + (col&7)   [col = c4, multiple of 4]
__global__ __launch_bounds__(256) void combine(const float* __restrict__ Opart,
                                               const float* __restrict__ lpart,
                                               unsigned short* __restrict__ Xo, int split) {
  const int idx = blockIdx.x * 256 + threadIdx.x;
  const int row = idx >> 6, c4 = (idx & 63) << 2, h = c4 >> 5;
  float l = 0.f;
  float4 o = {0.f, 0.f, 0.f, 0.f};
  for (int zz = 0; zz < split; ++zz) {
    l += lpart[(size_t)zz * 32768 + row * 8 + h];
    const float4 ov = *(const float4*)(Opart + (size_t)zz * 1048576 + (size_t)row * 256 + c4);
    o.x += ov.x; o.y += ov.y; o.z += ov.z; o.w += ov.w;
  }
  const float inv = 1.f / l;
  u16x4 pk = { f2bf(o.x * inv), f2bf(o.y * inv), f2bf(o.z * inv), f2bf(o.w * inv) };
  unsigned short* dst = Xo + (size_t)(row >> 4) * 4096 + h * 512 +
                        (row & 15) * 32 + ((c4 >> 3) & 3) * 8 + (c4 & 7);
  *(u16x4*)dst = pk;
}

// ---------------------------------------------------------------- proj_out
// A reads from fragment-packed Xp: contiguous 1KB wave-loads.
__global__ __launch_bounds__(256) void proj_out(const unsigned short* __restrict__ Xp,
                                                const unsigned short* __restrict__ Wb,
                                                const float* __restrict__ bias,
                                                float* __restrict__ out) {
  const int tid = threadIdx.x;
  const int w = tid >> 6, lane = tid & 63, x = lane & 15, g = lane >> 4;
  const int rbase = blockIdx.x << 4;
  const int cb = w << 6;
  const unsigned short* ap = Xp + (size_t)blockIdx.x * 4096 + x * 32 + g * 8;
  bf16x8 a[8];
#pragma unroll
  for (int k = 0; k < 8; ++k) a[k] = *(const bf16x8*)(ap + k * 512);
  f32x4 acc[4];
#pragma unroll
  for (int n = 0; n < 4; ++n) acc[n] = (f32x4){0.f, 0.f, 0.f, 0.f};
#pragma unroll
  for (int k = 0; k < 8; ++k)
#pragma unroll
    for (int n = 0; n < 4; ++n) {
      const bf16x8 bw = *(const bf16x8*)(Wb + (size_t)((w << 2) + n) * 4096 + k * 512 + x * 32 + g * 8);
      acc[n] = MFMA16(a[k], bw, acc[n]);
    }
#pragma unroll
  for (int n = 0; n < 4; ++n) {
    const float bv = bias[cb + n * 16 + x];
#pragma unroll
    for (int r = 0; r < 4; ++r)
      out[(size_t)(rbase + g * 4 + r) * 256 + cb + n * 16 + x] = acc[n][r] + bv;
  }
}

// ---------------------------------------------------------------- launch
extern "C" void kernel_launch(void* const* d_in, const int* in_sizes, int n_in,
                              void* d_out, int out_size, void* d_ws, size_t ws_size,
                              hipStream_t stream) {
  const float* q        = (const float*)d_in[0];
  const float* kv       = (const float*)d_in[1];
  const float* q_ape    = (const float*)d_in[2];
  const float* k_ape    = (const float*)d_in[3];
  const float* attn_pos = (const float*)d_in[4];
  const float* Wq       = (const float*)d_in[5];
  const float* Wk       = (const float*)d_in[6];
  const float* Wv       = (const float*)d_in[7];
  const float* Wp       = (const float*)d_in[8];
  const float* bp       = (const float*)d_in[9];
  float* out = (float*)d_out;

  unsigned short* wsb = (unsigned short*)d_ws;
  unsigned short* Wqb = wsb;                 // 4 x 65536 shorts (fragment-packed)
  unsigned short* Wkb = wsb + 65536;
  unsigned short* Wvb = wsb + 131072;
  unsigned short* Wpb = wsb + 196608;
  unsigned short* Qhp = wsb + 262144;        // [4][8][1024][32] head-packed
  unsigned short* Khp = wsb + 1310720;       // [4][8][4096][32]
  unsigned short* Vsp = wsb + 5505024;       // sigma-permuted V
  unsigned short* Xws = wsb + 9699328;       // fragment-packed X [256 blk][4096]
  unsigned short* kvp = wsb + 10747904;      // packed kv+ape (8MB)
  unsigned short* qp  = wsb + 14942208;      // packed q+ape  (2MB)

  const size_t L0  = 31981568ull;            // bytes of everything above
  const size_t PFB = 16777216ull;            // pf bf16 bytes
  const size_t PS  = 4325376ull;             // per-split Opart+lpart bytes
  int split; bool havepf;
  if      (ws_size >= L0 + PFB + 4 * PS) { split = 4; havepf = true; }
  else if (ws_size >= L0 + 4 * PS)       { split = 4; havepf = false; }
  else if (ws_size >= L0 + 2 * PS)       { split = 2; havepf = false; }
  else                                   { split = 1; havepf = false; }
  unsigned short* pfb = (unsigned short*)((char*)d_ws + L0);
  float* Opart = (float*)((char*)d_ws + L0 + (havepf ? PFB : 0));
  float* lpart = Opart + (size_t)split * 1048576;

  const int posBlocks = havepf ? 8192 : 0;
  prep_all<<<posBlocks + 128 + 2048 + 512, 256, 0, stream>>>(
      Wq, Wk, Wv, Wp, attn_pos, q, kv, q_ape, k_ape, wsb, pfb, kvp, qp, posBlocks);
  proj_qkv<<<1152, 256, 0, stream>>>(kvp, qp, Wqb, Wkb, Wvb, Qhp, Khp, Vsp);
  if (havepf)
    attn_fused<4, true><<<1024, 256, 0, stream>>>(Qhp, Khp, Vsp, pfb, Xws, Opart, lpart);
  else if (split == 4)
    attn_fused<4, false><<<1024, 256, 0, stream>>>(Qhp, Khp, Vsp, attn_pos, Xws, Opart, lpart);
  else if (split == 2)
    attn_fused<2, false><<<512, 256, 0, stream>>>(Qhp, Khp, Vsp, attn_pos, Xws, Opart, lpart);
  else
    attn_fused<1, false><<<256, 256, 0, stream>>>(Qhp, Khp, Vsp, attn_pos, Xws, Opart, lpart);
  if (split > 1) combine<<<1024, 256, 0, stream>>>(Opart, lpart, Xws, split);
  proj_out<<<256, 256, 0, stream>>>(Xws, Wpb, bp, out);
}

// Round 19
// 83.569 us; speedup vs baseline: 1.4417x; 1.0590x over previous
//
#include <hip/hip_runtime.h>

// Fused cross-attention, MI355X gfx950. B=4, LQ=1024, LKV=4096, C=256, H=8, d=32, Z=1024.
//
// R19 = R18 + LDS K/V staging in attn: all 4 waves of a block share identical
// K/V tiles (same b,h,z) — R18 loaded them 4x redundantly per wave and held
// ka/va in 32 persistent VGPRs. Now: 4KB K-tile + 4KB V-tile double-buffered
// in LDS, staged once per block (each wave loads its 1KB quarter issue-early,
// ds_writes into the idle buffer late, ONE __syncthreads per tile). K tiles
// re-laid fragment-major [c][g][x][8] so ds_read_b128 is conflict-free
// (consecutive lanes contiguous 16B); V tile layout was already fragment-major.
//
//   prep_all: W pack + pos pack (bf16*log2e) + kv pack + q pack (elementwise)
//   proj_qkv: Khp frag-major tiles; Vsp (sigma-permuted); Qhp[b][h][qrow][32]
//   attn:     fixed-max (M=0) flash attention, KV-split 4, LDS-staged, QG=2
//   combine:  sum partials, normalize -> Xp (fragment-packed bf16)
//   proj_out: out = fp32(Xp @ Wp^T + bp), packed A reads
//
// mfma_f32_16x16x32_bf16 layouts (m89-verified):
//   A: row=l&15, k=(l>>4)*8+i ; B: col=l&15, k=(l>>4)*8+i ; C: col=l&15, row=(l>>4)*4+r

typedef __attribute__((ext_vector_type(8))) short bf16x8;
typedef __attribute__((ext_vector_type(4))) float f32x4;
typedef __attribute__((ext_vector_type(4))) unsigned short u16x4;

#define MFMA16(a, b, c) __builtin_amdgcn_mfma_f32_16x16x32_bf16((a), (b), (c), 0, 0, 0)

__device__ __forceinline__ unsigned short f2bf(float f) {
  return __builtin_bit_cast(unsigned short, static_cast<__bf16>(f));  // RNE
}
__device__ __forceinline__ float bf2f(unsigned short u) {
  return __builtin_bit_cast(float, ((unsigned)u) << 16);
}

// ---------------------------------------------------------------- prep_all
__global__ __launch_bounds__(256) void prep_all(const float* __restrict__ Wq,
                                                const float* __restrict__ Wk,
                                                const float* __restrict__ Wv,
                                                const float* __restrict__ Wp,
                                                const float* __restrict__ pos,
                                                const float* __restrict__ Xq,
                                                const float* __restrict__ Xkv,
                                                const float* __restrict__ q_ape,
                                                const float* __restrict__ k_ape,
                                                unsigned short* __restrict__ wout,
                                                unsigned short* __restrict__ pfb,
                                                unsigned short* __restrict__ kvp,
                                                unsigned short* __restrict__ qp,
                                                int posBlocks) {
  int bx = blockIdx.x;
  if (bx < posBlocks) {
    const int s4 = bx * 256 + threadIdx.x;  // 2,097,152 threads, 4 floats each
    const int zk4 = s4 & 255, q = (s4 >> 8) & 1023, h = s4 >> 18;
    const float4 v = *(const float4*)(pos + ((size_t)s4 << 2));
    const int kt = zk4 >> 4, c = (zk4 >> 2) & 3, g = zk4 & 3;
    const float L = 1.4426950408889634f;
    u16x4 o = { f2bf(v.x * L), f2bf(v.y * L), f2bf(v.z * L), f2bf(v.w * L) };
    *(u16x4*)(pfb + (size_t)((h << 6) + (q >> 4)) * 16384 + ((kt << 2) + c) * 256 + ((q & 15) << 4) + (g << 2)) = o;
    return;
  }
  bx -= posBlocks;
  if (bx < 128) {
    const int idx = bx * 256 + threadIdx.x;  // 32768 threads
    const int which = idx >> 13, rem = idx & 8191;
    const int o = rem >> 5, colb = (rem & 31) << 3;
    const float* src = (which == 0) ? Wq : (which == 1) ? Wk : (which == 2) ? Wv : Wp;
    float4 v0 = *(const float4*)(src + (size_t)o * 256 + colb);
    float4 v1 = *(const float4*)(src + (size_t)o * 256 + colb + 4);
    if (which == 0) {  // fold softmax scale and log2(e) into Wq
      const float qs = 0.17677669529663687f * 1.4426950408889634f;
      v0.x *= qs; v0.y *= qs; v0.z *= qs; v0.w *= qs;
      v1.x *= qs; v1.y *= qs; v1.z *= qs; v1.w *= qs;
    }
    const int n = o >> 4, x = o & 15, k = colb >> 5, g = (colb & 31) >> 3;
    unsigned short* dst = wout + (which << 16) + n * 4096 + k * 512 + x * 32 + g * 8;
    u16x4 a = { f2bf(v0.x), f2bf(v0.y), f2bf(v0.z), f2bf(v0.w) };
    u16x4 b = { f2bf(v1.x), f2bf(v1.y), f2bf(v1.z), f2bf(v1.w) };
    *(u16x4*)dst = a;
    *(u16x4*)(dst + 4) = b;
    return;
  }
  bx -= 128;
  if (bx < 2048) {
    const int idx = bx * 256 + threadIdx.x;  // 524,288 threads: 16384 rows x 32 col-chunks
    const int row = idx >> 5, c8 = idx & 31;
    const int col = c8 << 3, lq = row & 4095;
    const float* xp = Xkv + (size_t)row * 256 + col;
    float4 v0 = *(const float4*)xp, v1 = *(const float4*)(xp + 4);
    if (lq >= 1024) {  // k_ape covers kv rows [Z, LKV)
      const float* ap = k_ape + (size_t)(lq - 1024) * 256 + col;
      const float4 a0 = *(const float4*)ap, a1 = *(const float4*)(ap + 4);
      v0.x += a0.x; v0.y += a0.y; v0.z += a0.z; v0.w += a0.w;
      v1.x += a1.x; v1.y += a1.y; v1.z += a1.z; v1.w += a1.w;
    }
    const int k = c8 >> 2, g = c8 & 3;
    unsigned short* dst = kvp + (size_t)(row >> 4) * 4096 + k * 512 + (row & 15) * 32 + g * 8;
    u16x4 a = { f2bf(v0.x), f2bf(v0.y), f2bf(v0.z), f2bf(v0.w) };
    u16x4 b = { f2bf(v1.x), f2bf(v1.y), f2bf(v1.z), f2bf(v1.w) };
    *(u16x4*)dst = a;
    *(u16x4*)(dst + 4) = b;
    return;
  }
  bx -= 2048;
  {
    const int idx = bx * 256 + threadIdx.x;  // 131,072 threads: 4096 rows x 32 chunks
    const int row = idx >> 5, c8 = idx & 31;
    const int col = c8 << 3, arow = row & 1023;
    const float* xp = Xq + (size_t)row * 256 + col;
    const float* ap = q_ape + (size_t)arow * 256 + col;
    const float4 v0 = *(const float4*)xp, v1 = *(const float4*)(xp + 4);
    const float4 a0 = *(const float4*)ap, a1 = *(const float4*)(ap + 4);
    const int k = c8 >> 2, g = c8 & 3;
    unsigned short* dst = qp + (size_t)(row >> 4) * 4096 + k * 512 + (row & 15) * 32 + g * 8;
    u16x4 a = { f2bf(v0.x + a0.x), f2bf(v0.y + a0.y), f2bf(v0.z + a0.z), f2bf(v0.w + a0.w) };
    u16x4 b = { f2bf(v1.x + a1.x), f2bf(v1.y + a1.y), f2bf(v1.z + a1.z), f2bf(v1.w + a1.w) };
    *(u16x4*)dst = a;
    *(u16x4*)(dst + 4) = b;
  }
}

// ---------------------------------------------------------------- proj_qkv
// blocks [0,512): K -> Khp FRAGMENT-MAJOR tiles: per (b,h), tile T (64 keys) is
//   2048 shorts: [c=key>>4&3][g=dim>>3][x=key&15][i=dim&7]
// blocks [512,1024): V -> Vsp sigma store (already fragment-major per tile)
// blocks [1024,1152): Q -> Qhp[b][h][qrow][32] (head-packed)
__global__ __launch_bounds__(256, 4) void proj_qkv(const unsigned short* __restrict__ kvp,
                                                   const unsigned short* __restrict__ qp,
                                                   const unsigned short* __restrict__ Wqb,
                                                   const unsigned short* __restrict__ Wkb,
                                                   const unsigned short* __restrict__ Wvb,
                                                   unsigned short* __restrict__ Qhp,
                                                   unsigned short* __restrict__ Khp,
                                                   unsigned short* __restrict__ Vsp) {
  const int tid = threadIdx.x;
  const int w = tid >> 6, lane = tid & 63, x = lane & 15, g = lane >> 4;
  const int rg = w & 1, nh = w >> 1;
  const int bx = blockIdx.x;
  if (bx < 1024) {
    const bool isV = bx >= 512;
    const int bk = isV ? bx - 512 : bx;
    const int rbase = bk * 32 + rg * 16;
    const unsigned short* ap = kvp + (size_t)(rbase >> 4) * 4096 + x * 32 + g * 8;
    bf16x8 a[8];
#pragma unroll
    for (int k = 0; k < 8; ++k) a[k] = *(const bf16x8*)(ap + k * 512);
    const unsigned short* Wb = isV ? Wvb : Wkb;
    f32x4 acc[8];
#pragma unroll
    for (int n = 0; n < 8; ++n) acc[n] = (f32x4){0.f, 0.f, 0.f, 0.f};
#pragma unroll
    for (int k = 0; k < 8; ++k)
#pragma unroll
      for (int n0 = 0; n0 < 8; ++n0) {
        const bf16x8 bw = *(const bf16x8*)(Wb + (size_t)(nh * 8 + n0) * 4096 + k * 512 + x * 32 + g * 8);
        acc[n0] = MFMA16(a[k], bw, acc[n0]);
      }
    if (!isV) {
      // fragment-major store: key = (rbase&4095)+g*4+r -> T2,c2 const per wave,
      // x2 = g*4+r; dim = ((n&1)<<4)+x -> g2 = ((n&1)<<1)+(x>>3), i2 = x&7.
      const int b2 = rbase >> 12;
      const int T2 = (rbase & 4095) >> 6, c2 = (rbase >> 4) & 3;
#pragma unroll
      for (int n0 = 0; n0 < 8; ++n0) {
        const int n = nh * 8 + n0, hh = n >> 1;
        const int g2 = ((n & 1) << 1) + (x >> 3), i2 = x & 7;
        unsigned short* kp = Khp + (size_t)(b2 * 8 + hh) * 131072 +
                             T2 * 2048 + (c2 * 4 + g2) * 128 + i2;
#pragma unroll
        for (int r = 0; r < 4; ++r)
          kp[(g * 4 + r) * 8] = f2bf(acc[n0][r]);
      }
    } else {
      // sigma: key slot m=16c0+4g+r stored at ks=c0&1, i=4*(c0>>1)+r
      const int b2 = rbase >> 12, T = (rbase >> 6) & 63, c0 = (rbase >> 4) & 3;
      const int ks = c0 & 1, ih = (c0 >> 1) << 2;
#pragma unroll
      for (int n0 = 0; n0 < 8; ++n0) {
        const int n = nh * 8 + n0, hh = n >> 1, dh = n & 1;
        u16x4 o = { f2bf(acc[n0][0]), f2bf(acc[n0][1]), f2bf(acc[n0][2]), f2bf(acc[n0][3]) };
        *(u16x4*)(Vsp + (size_t)(b2 * 8 + hh) * 131072 + T * 2048 + ks * 1024 + dh * 512 + g * 128 + x * 8 + ih) = o;
      }
    }
  } else {
    const int bq = bx - 1024;  // 0..127
    const int rbase = bq * 32 + rg * 16;
    const unsigned short* ap = qp + (size_t)(rbase >> 4) * 4096 + x * 32 + g * 8;
    bf16x8 a[8];
#pragma unroll
    for (int k = 0; k < 8; ++k) a[k] = *(const bf16x8*)(ap + k * 512);
    f32x4 acc[8];
#pragma unroll
    for (int n = 0; n < 8; ++n) acc[n] = (f32x4){0.f, 0.f, 0.f, 0.f};
#pragma unroll
    for (int k = 0; k < 8; ++k)
#pragma unroll
      for (int n0 = 0; n0 < 8; ++n0) {
        const bf16x8 bw = *(const bf16x8*)(Wqb + (size_t)(nh * 8 + n0) * 4096 + k * 512 + x * 32 + g * 8);
        acc[n0] = MFMA16(a[k], bw, acc[n0]);
      }
    // head-packed store: Qhp[b][h][qrow][32]
    const int b2 = rbase >> 10, qr0 = (rbase & 1023) + g * 4;
#pragma unroll
    for (int n0 = 0; n0 < 8; ++n0) {
      const int n = nh * 8 + n0, hh = n >> 1, dd = ((n & 1) << 4) + x;
      unsigned short* qpn = Qhp + (size_t)(b2 * 8 + hh) * 32768;
#pragma unroll
      for (int r = 0; r < 4; ++r)
        qpn[(size_t)(qr0 + r) * 32 + dd] = f2bf(acc[n0][r]);
    }
  }
}

// ---------------------------------------------------------------- attn
// 1-D grid of 256*SPLIT blocks, XCD decode h=bid&7 (bid%8 -> XCD round-robin).
// b=(bid>>3)&3, qt=(bid>>5)&7, z=bid>>8. Wave: 32 q-rows (QG=2), groups
// SEQUENTIAL. K/V tiles (4KB each) double-buffered in LDS, staged once per
// block: each wave loads its 1KB quarter early, ds_writes into the idle
// buffer after compute, ONE __syncthreads per tile. ds_reads conflict-free
// (fragment-major tiles: consecutive lanes contiguous 16B). nt partial stores.
template <int SPLIT, bool PF>
__global__ __launch_bounds__(256, 4) void
attn_fused(const unsigned short* __restrict__ Qhp,
           const unsigned short* __restrict__ Khp,
           const unsigned short* __restrict__ Vsp,
           const void* __restrict__ pos,
           unsigned short* __restrict__ Xo,
           float* __restrict__ Opart,
           float* __restrict__ lpart) {
  __shared__ unsigned short ldsK[2][2048];
  __shared__ unsigned short ldsV[2][2048];
  const int tid = threadIdx.x;
  const int w = tid >> 6, lane = tid & 63, x = lane & 15, g = lane >> 4;
  const int bid = blockIdx.x;
  const int h = bid & 7, b = (bid >> 3) & 3, qt = (bid >> 5) & 7, z = bid >> 8;
  const int qrow0 = qt * 128 + w * 32;
  const int NT = 64 / SPLIT;

  const unsigned short* Qpl = Qhp + (size_t)(b * 8 + h) * 32768;
  const bf16x8 aq0 = *(const bf16x8*)(Qpl + (size_t)(qrow0 + x) * 32 + g * 8);
  const bf16x8 aq1 = *(const bf16x8*)(Qpl + (size_t)(qrow0 + 16 + x) * 32 + g * 8);
  const unsigned short* Ksrc = Khp + (size_t)(b * 8 + h) * 131072;  // 2048-short tiles
  const unsigned short* Vsrc = Vsp + (size_t)(b * 8 + h) * 131072;
  const int stageoff = w * 512 + lane * 8;  // this wave's 1KB quarter, 16B/lane
  // PF: bf16 pre-scaled bias, fragment-packed. !PF: raw fp32 [h][q][zkey].
  const unsigned short* pq0 = PF ? (const unsigned short*)pos + (size_t)((h << 6) + (qt << 3) + (w << 1)) * 16384 : nullptr;
  const unsigned short* pq1 = PF ? pq0 + 16384 : nullptr;
  const float* pr0 = PF ? nullptr : (const float*)pos + (size_t)((h << 10) + qrow0 + x) * 1024;
  const float* pr1 = PF ? nullptr : (const float*)pos + (size_t)((h << 10) + qrow0 + 16 + x) * 1024;
  const f32x4 zc = {0.f, 0.f, 0.f, 0.f};

  f32x4 o00 = zc, o01 = zc, o10 = zc, o11 = zc;
  float ls0 = 0.f, ls1 = 0.f;

  // prologue: stage tile z into buffer 0
  {
    const bf16x8 kq = *(const bf16x8*)(Ksrc + (z << 11) + stageoff);
    const bf16x8 vq = *(const bf16x8*)(Vsrc + (z << 11) + stageoff);
    *(bf16x8*)(&ldsK[0][stageoff]) = kq;
    *(bf16x8*)(&ldsV[0][stageoff]) = vq;
  }
  __syncthreads();

// One q-group: QK (ka from TILE scope) -> [bias] -> exp2/lsum -> pack -> PV
// (va read from LDS, transient).
#define GROUP(AQ, PQ, PR, LS, OA, OB, T, BIAS, CUR)                                          \
  do {                                                                                       \
    f32x4 s[4];                                                                              \
    _Pragma("unroll")                                                                        \
    for (int c = 0; c < 4; ++c) s[c] = MFMA16(ka[c], AQ, zc);                                \
    if (BIAS) {                                                                              \
      if (PF) {                                                                              \
        _Pragma("unroll")                                                                    \
        for (int c = 0; c < 4; ++c) {                                                        \
          const u16x4 p = *(const u16x4*)(PQ + ((T) << 10) + (c << 8) + (x << 4) + (g << 2)); \
          s[c][0] += bf2f(p[0]); s[c][1] += bf2f(p[1]);                                      \
          s[c][2] += bf2f(p[2]); s[c][3] += bf2f(p[3]);                                      \
        }                                                                                    \
      } else {                                                                               \
        const float LOG2E = 1.4426950408889634f;                                             \
        _Pragma("unroll")                                                                    \
        for (int c = 0; c < 4; ++c) {                                                        \
          const float4 p = *(const float4*)(PR + ((T) << 6) + c * 16 + g * 4);               \
          s[c][0] = fmaf(p.x, LOG2E, s[c][0]); s[c][1] = fmaf(p.y, LOG2E, s[c][1]);          \
          s[c][2] = fmaf(p.z, LOG2E, s[c][2]); s[c][3] = fmaf(p.w, LOG2E, s[c][3]);          \
        }                                                                                    \
      }                                                                                      \
    }                                                                                        \
    _Pragma("unroll")                                                                        \
    for (int c = 0; c < 4; ++c)                                                              \
      _Pragma("unroll")                                                                      \
      for (int r = 0; r < 4; ++r) {                                                          \
        s[c][r] = __builtin_amdgcn_exp2f(s[c][r]); LS += s[c][r];                            \
      }                                                                                      \
    bf16x8 pa0, pa1;                                                                         \
    _Pragma("unroll")                                                                        \
    for (int r = 0; r < 4; ++r) {                                                            \
      pa0[r] = (short)f2bf(s[0][r]); pa0[4 + r] = (short)f2bf(s[2][r]);                      \
      pa1[r] = (short)f2bf(s[1][r]); pa1[4 + r] = (short)f2bf(s[3][r]);                      \
    }                                                                                        \
    OA = MFMA16(pa0, *(const bf16x8*)(&ldsV[CUR][g * 128 + x * 8]), OA);                     \
    OB = MFMA16(pa0, *(const bf16x8*)(&ldsV[CUR][512 + g * 128 + x * 8]), OB);               \
    OA = MFMA16(pa1, *(const bf16x8*)(&ldsV[CUR][1024 + g * 128 + x * 8]), OA);              \
    OB = MFMA16(pa1, *(const bf16x8*)(&ldsV[CUR][1536 + g * 128 + x * 8]), OB);              \
  } while (0)

#define TILE(T, BIAS, CUR)                                                                   \
  do {                                                                                       \
    const int tp = ((T) + SPLIT <= 63) ? (T) + SPLIT : (T);                                  \
    const bf16x8 kq = *(const bf16x8*)(Ksrc + (tp << 11) + stageoff);                        \
    const bf16x8 vq = *(const bf16x8*)(Vsrc + (tp << 11) + stageoff);                        \
    bf16x8 ka[4];                                                                            \
    _Pragma("unroll")                                                                        \
    for (int c = 0; c < 4; ++c)                                                              \
      ka[c] = *(const bf16x8*)(&ldsK[CUR][(c * 4 + g) * 128 + x * 8]);                       \
    GROUP(aq0, pq0, pr0, ls0, o00, o01, T, BIAS, CUR);                                       \
    GROUP(aq1, pq1, pr1, ls1, o10, o11, T, BIAS, CUR);                                       \
    *(bf16x8*)(&ldsK[(CUR) ^ 1][stageoff]) = kq;                                             \
    *(bf16x8*)(&ldsV[(CUR) ^ 1][stageoff]) = vq;                                             \
    __syncthreads();                                                                         \
  } while (0)

  const int nb = 16 / SPLIT;  // biased iterations (even for SPLIT in {1,2,4,8})
  int t = z;
  for (int i = 0; i < nb; i += 2) {
    TILE(t, true, 0);  t += SPLIT;
    TILE(t, true, 1);  t += SPLIT;
  }
  for (int i = nb; i < NT; i += 2) {
    TILE(t, false, 0); t += SPLIT;
    TILE(t, false, 1); t += SPLIT;
  }
#undef TILE
#undef GROUP

  ls0 += __shfl_xor(ls0, 16); ls0 += __shfl_xor(ls0, 32);
  ls1 += __shfl_xor(ls1, 16); ls1 += __shfl_xor(ls1, 32);

  if (SPLIT == 1) {
    // fragment-packed X write (matches proj_out's packed A reads)
    const float inv0 = 1.f / ls0, inv1 = 1.f / ls1;
    const int rowblk = (b << 6) + (qt << 3) + (w << 1);
#pragma unroll
    for (int r = 0; r < 4; ++r) {
      const float ir0 = __shfl(inv0, g * 4 + r, 64);
      const float ir1 = __shfl(inv1, g * 4 + r, 64);
      unsigned short* d0 = Xo + (size_t)rowblk * 4096 + h * 512 + (g * 4 + r) * 32;
      unsigned short* d1 = Xo + (size_t)(rowblk + 1) * 4096 + h * 512 + (g * 4 + r) * 32;
      d0[x] = f2bf(o00[r] * ir0);
      d0[16 + x] = f2bf(o01[r] * ir0);
      d1[x] = f2bf(o10[r] * ir1);
      d1[16 + x] = f2bf(o11[r] * ir1);
    }
  } else {
    if (g == 0) {
      __builtin_nontemporal_store(ls0, &lpart[(size_t)z * 32768 + ((b << 10) + qrow0 + x) * 8 + h]);
      __builtin_nontemporal_store(ls1, &lpart[(size_t)z * 32768 + ((b << 10) + qrow0 + 16 + x) * 8 + h]);
    }
#pragma unroll
    for (int r = 0; r < 4; ++r) {
      const size_t orow0 = (size_t)z * 1048576 + (size_t)((b << 10) + qrow0 + g * 4 + r) * 256 + h * 32;
      const size_t orow1 = (size_t)z * 1048576 + (size_t)((b << 10) + qrow0 + 16 + g * 4 + r) * 256 + h * 32;
      __builtin_nontemporal_store(o00[r], &Opart[orow0 + x]);
      __builtin_nontemporal_store(o01[r], &Opart[orow0 + 16 + x]);
      __builtin_nontemporal_store(o10[r], &Opart[orow1 + x]);
      __builtin_nontemporal_store(o11[r], &Opart[orow1 + 16 + x]);
    }
  }
}

// ---------------------------------------------------------------- combine
// Writes Xp in fragment-packed layout: off = (row>>4)*4096 + (col>>5)*512 +
// (row&15)*32 + ((col>>3)&3)*8 + (col&7)   [col = c4, multiple of 4]
__global__ __launch_bounds__(256) void combine(const float* __restrict__ Opart,
                                               const float* __restrict__ lpart,
                                               unsigned short* __restrict__ Xo, int split) {
  const int idx = blockIdx.x * 256 + threadIdx.x;
  const int row = idx >> 6, c4 = (idx & 63) << 2, h = c4 >> 5;
  float l = 0.f;
  float4 o = {0.f, 0.f, 0.f, 0.f};
  for (int zz = 0; zz < split; ++zz) {
    l += lpart[(size_t)zz * 32768 + row * 8 + h];
    const float4 ov = *(const float4*)(Opart + (size_t)zz * 1048576 + (size_t)row * 256 + c4);
    o.x += ov.x; o.y += ov.y; o.z += ov.z; o.w += ov.w;
  }
  const float inv = 1.f / l;
  u16x4 pk = { f2bf(o.x * inv), f2bf(o.y * inv), f2bf(o.z * inv), f2bf(o.w * inv) };
  unsigned short* dst = Xo + (size_t)(row >> 4) * 4096 + h * 512 +
                        (row & 15) * 32 + ((c4 >> 3) & 3) * 8 + (c4 & 7);
  *(u16x4*)dst = pk;
}

// ---------------------------------------------------------------- proj_out
// A reads from fragment-packed Xp: contiguous 1KB wave-loads.
__global__ __launch_bounds__(256) void proj_out(const unsigned short* __restrict__ Xp,
                                                const unsigned short* __restrict__ Wb,
                                                const float* __restrict__ bias,
                                                float* __restrict__ out) {
  const int tid = threadIdx.x;
  const int w = tid >> 6, lane = tid & 63, x = lane & 15, g = lane >> 4;
  const int rbase = blockIdx.x << 4;
  const int cb = w << 6;
  const unsigned short* ap = Xp + (size_t)blockIdx.x * 4096 + x * 32 + g * 8;
  bf16x8 a[8];
#pragma unroll
  for (int k = 0; k < 8; ++k) a[k] = *(const bf16x8*)(ap + k * 512);
  f32x4 acc[4];
#pragma unroll
  for (int n = 0; n < 4; ++n) acc[n] = (f32x4){0.f, 0.f, 0.f, 0.f};
#pragma unroll
  for (int k = 0; k < 8; ++k)
#pragma unroll
    for (int n = 0; n < 4; ++n) {
      const bf16x8 bw = *(const bf16x8*)(Wb + (size_t)((w << 2) + n) * 4096 + k * 512 + x * 32 + g * 8);
      acc[n] = MFMA16(a[k], bw, acc[n]);
    }
#pragma unroll
  for (int n = 0; n < 4; ++n) {
    const float bv = bias[cb + n * 16 + x];
#pragma unroll
    for (int r = 0; r < 4; ++r)
      out[(size_t)(rbase + g * 4 + r) * 256 + cb + n * 16 + x] = acc[n][r] + bv;
  }
}

// ---------------------------------------------------------------- launch
extern "C" void kernel_launch(void* const* d_in, const int* in_sizes, int n_in,
                              void* d_out, int out_size, void* d_ws, size_t ws_size,
                              hipStream_t stream) {
  const float* q        = (const float*)d_in[0];
  const float* kv       = (const float*)d_in[1];
  const float* q_ape    = (const float*)d_in[2];
  const float* k_ape    = (const float*)d_in[3];
  const float* attn_pos = (const float*)d_in[4];
  const float* Wq       = (const float*)d_in[5];
  const float* Wk       = (const float*)d_in[6];
  const float* Wv       = (const float*)d_in[7];
  const float* Wp       = (const float*)d_in[8];
  const float* bp       = (const float*)d_in[9];
  float* out = (float*)d_out;

  unsigned short* wsb = (unsigned short*)d_ws;
  unsigned short* Wqb = wsb;                 // 4 x 65536 shorts (fragment-packed)
  unsigned short* Wkb = wsb + 65536;
  unsigned short* Wvb = wsb + 131072;
  unsigned short* Wpb = wsb + 196608;
  unsigned short* Qhp = wsb + 262144;        // [4][8][1024][32] head-packed
  unsigned short* Khp = wsb + 1310720;       // [4][8] frag-major 2048-short tiles
  unsigned short* Vsp = wsb + 5505024;       // sigma-permuted V
  unsigned short* Xws = wsb + 9699328;       // fragment-packed X [256 blk][4096]
  unsigned short* kvp = wsb + 10747904;      // packed kv+ape (8MB)
  unsigned short* qp  = wsb + 14942208;      // packed q+ape  (2MB)

  const size_t L0  = 31981568ull;            // bytes of everything above
  const size_t PFB = 16777216ull;            // pf bf16 bytes
  const size_t PS  = 4325376ull;             // per-split Opart+lpart bytes
  int split; bool havepf;
  if      (ws_size >= L0 + PFB + 4 * PS) { split = 4; havepf = true; }
  else if (ws_size >= L0 + 4 * PS)       { split = 4; havepf = false; }
  else if (ws_size >= L0 + 2 * PS)       { split = 2; havepf = false; }
  else                                   { split = 1; havepf = false; }
  unsigned short* pfb = (unsigned short*)((char*)d_ws + L0);
  float* Opart = (float*)((char*)d_ws + L0 + (havepf ? PFB : 0));
  float* lpart = Opart + (size_t)split * 1048576;

  const int posBlocks = havepf ? 8192 : 0;
  prep_all<<<posBlocks + 128 + 2048 + 512, 256, 0, stream>>>(
      Wq, Wk, Wv, Wp, attn_pos, q, kv, q_ape, k_ape, wsb, pfb, kvp, qp, posBlocks);
  proj_qkv<<<1152, 256, 0, stream>>>(kvp, qp, Wqb, Wkb, Wvb, Qhp, Khp, Vsp);
  if (havepf)
    attn_fused<4, true><<<1024, 256, 0, stream>>>(Qhp, Khp, Vsp, pfb, Xws, Opart, lpart);
  else if (split == 4)
    attn_fused<4, false><<<1024, 256, 0, stream>>>(Qhp, Khp, Vsp, attn_pos, Xws, Opart, lpart);
  else if (split == 2)
    attn_fused<2, false><<<512, 256, 0, stream>>>(Qhp, Khp, Vsp, attn_pos, Xws, Opart, lpart);
  else
    attn_fused<1, false><<<256, 256, 0, stream>>>(Qhp, Khp, Vsp, attn_pos, Xws, Opart, lpart);
  if (split > 1) combine<<<1024, 256, 0, stream>>>(Opart, lpart, Xws, split);
  proj_out<<<256, 256, 0, stream>>>(Xws, Wpb, bp, out);
}